// Round 2
// baseline (3171.084 us; speedup 1.0000x reference)
//
#include <hip/hip_runtime.h>

// Problem constants
#define N_   1024
#define R_   100
#define D_   256
#define T_   14
#define H_   8
#define DH_  32
#define MM_  600
#define OBJ_ 36

// ---------------------------------------------------------------------------
// piecewise-linear map helper: tables (w, cs) each 17 entries per row
__device__ __forceinline__ float plin_f(const float* __restrict__ w,
                                        const float* __restrict__ cs, float x) {
  float xc = fminf(fmaxf(x, 0.f), 1.f);
  float y  = 16.f * xc;
  float fy = floorf(y);
  int   i  = (int)fy;              // 0..16
  float f  = y - fy;
  int   ip = i + 1; if (ip > 16) ip = 16;
  return cs[i] + f * w[ip];
}

// ---------------------------------------------------------------------------
// prep plin tables: w = |pw| with w[0]=0, normalized; cs = cumsum(w)
__global__ void prep_plin(const float* __restrict__ pw, float* __restrict__ plw,
                          float* __restrict__ plc) {
  int p = threadIdx.x;
  if (p < 8) {
    float w[17];
    float sum = 0.f;
    w[0] = 0.f;
    for (int k = 1; k < 17; ++k) { w[k] = fabsf(pw[p*17 + k]); sum += w[k]; }
    float inv = 1.f / sum;
    float c = 0.f;
    for (int k = 0; k < 17; ++k) {
      float wk = w[k] * inv;
      c += wk;
      plw[p*17 + k] = wk;
      plc[p*17 + k] = c;
    }
  }
}

// ---------------------------------------------------------------------------
// fused QKV bias: c[i] = in_b[i] + sum_o in_w[i][o]*b{q,k,v}[o]
__global__ void fuse_c(const float* __restrict__ in_w, const float* __restrict__ in_b,
                       const float* __restrict__ bq, const float* __restrict__ bk,
                       const float* __restrict__ bv, float* __restrict__ c) {
  int i = blockIdx.x * blockDim.x + threadIdx.x;
  if (i < 768) {
    const float* bsel = (i < 256) ? bq : ((i < 512) ? bk : bv);
    float acc = in_b[i];
    for (int o = 0; o < 256; ++o) acc += in_w[(size_t)i*256 + o] * bsel[o];
    c[i] = acc;
  }
}

// fused QKV weight: A[i][j] = sum_o in_w[i][o] * W{q,k,v}[o][j]
__global__ __launch_bounds__(256) void fuse_A(const float* __restrict__ in_w,
    const float* __restrict__ Wq, const float* __restrict__ Wk,
    const float* __restrict__ Wv, float* __restrict__ A) {
  int i = blockIdx.x;        // 0..767
  int j = threadIdx.x;       // 0..255
  const float* Wsel = (i < 256) ? Wq : ((i < 512) ? Wk : Wv);
  __shared__ float row[256];
  row[j] = in_w[(size_t)i*256 + j];
  __syncthreads();
  float acc = 0.f;
  for (int o = 0; o < 256; ++o) acc += row[o] * Wsel[(size_t)o*256 + j];
  A[(size_t)i*256 + j] = acc;
}

// ---------------------------------------------------------------------------
// C[m][o] = sum_k X[m][k]*W[o][k] + bias[o].  Tiles 64x64x16, 256 thr, 4x4/thr.
template<bool BOUND_N>
__global__ __launch_bounds__(256) void gemm_xt(const float* __restrict__ X,
    const float* __restrict__ W, const float* __restrict__ bias,
    float* __restrict__ C, int M, int K, int O) {
  __shared__ float Xs[64][17];
  __shared__ float Ws[64][17];
  const int bm = blockIdx.x * 64;
  const int bn = blockIdx.y * 64;
  const int tid = threadIdx.x;
  const int tn = tid & 15, tm = tid >> 4;
  float acc[4][4] = {};
  for (int k0 = 0; k0 < K; k0 += 16) {
#pragma unroll
    for (int l = 0; l < 4; ++l) {
      int idx = tid + l*256;
      int r = idx >> 4, cc = idx & 15;
      Xs[r][cc] = X[(size_t)(bm + r)*K + (k0 + cc)];
      int o = bn + r;
      float wv = 0.f;
      if (!BOUND_N || o < O) wv = W[(size_t)o*K + (k0 + cc)];
      Ws[r][cc] = wv;
    }
    __syncthreads();
#pragma unroll
    for (int kk = 0; kk < 16; ++kk) {
      float a[4], b[4];
#pragma unroll
      for (int i = 0; i < 4; ++i) a[i] = Xs[tm*4 + i][kk];
#pragma unroll
      for (int j = 0; j < 4; ++j) b[j] = Ws[tn*4 + j][kk];
#pragma unroll
      for (int i = 0; i < 4; ++i)
#pragma unroll
        for (int j = 0; j < 4; ++j) acc[i][j] += a[i] * b[j];
    }
    __syncthreads();
  }
#pragma unroll
  for (int i = 0; i < 4; ++i) {
    size_t m = (size_t)(bm + tm*4 + i);
#pragma unroll
    for (int j = 0; j < 4; ++j) {
      int o = bn + tn*4 + j;
      if (!BOUND_N || o < O) C[m*(size_t)O + o] = acc[i][j] + bias[o];
    }
  }
}

// ---------------------------------------------------------------------------
// attention: one block per (local n, h).  qkv layout (nc, r, 768): q|k|v each 256.
__global__ __launch_bounds__(256) void attn_kernel(const float* __restrict__ qkv,
                                                   float* __restrict__ ao) {
  const int n = blockIdx.x >> 3;   // chunk-local
  const int h = blockIdx.x & 7;
  __shared__ float qs[100][33], ks[100][33], vs[100][33];
  __shared__ float at[25][100];
  const float scale = 0.17677669529663687f;  // 1/sqrt(32)
  const int tid = threadIdx.x;
  const float* base = qkv + (size_t)n * 100 * 768;
  for (int idx = tid; idx < 3200; idx += 256) {
    int r = idx >> 5, d = idx & 31;
    const float* p = base + (size_t)r*768 + h*32 + d;
    qs[r][d] = p[0];
    ks[r][d] = p[256];
    vs[r][d] = p[512];
  }
  __syncthreads();
  for (int c0 = 0; c0 < 100; c0 += 25) {
    for (int idx = tid; idx < 2500; idx += 256) {
      int i = idx / 100, j = idx % 100;
      float acc = 0.f;
#pragma unroll
      for (int k2 = 0; k2 < 32; ++k2) acc += qs[c0 + i][k2] * ks[j][k2];
      at[i][j] = acc * scale;
    }
    __syncthreads();
    if (tid < 25) {
      float m = -1e30f;
      for (int j = 0; j < 100; ++j) m = fmaxf(m, at[tid][j]);
      float s = 0.f;
      for (int j = 0; j < 100; ++j) { float e = __expf(at[tid][j] - m); at[tid][j] = e; s += e; }
      float inv = 1.f / s;
      for (int j = 0; j < 100; ++j) at[tid][j] *= inv;
    }
    __syncthreads();
    for (int idx = tid; idx < 800; idx += 256) {
      int r = idx >> 5, d = idx & 31;
      float acc = 0.f;
      for (int j = 0; j < 100; ++j) acc += at[r][j] * vs[j][d];
      ao[((size_t)n*100 + c0 + r)*256 + h*32 + d] = acc;
    }
    __syncthreads();
  }
}

// ---------------------------------------------------------------------------
// layernorm in-place: one block (256 thr) per row of 256
__global__ __launch_bounds__(256) void ln_kernel(float* __restrict__ x,
    const float* __restrict__ g, const float* __restrict__ b) {
  size_t m = blockIdx.x;
  int tid = threadIdx.x;
  float v = x[m*256 + tid];
  __shared__ float red[4];
  float s = v;
  for (int o = 32; o > 0; o >>= 1) s += __shfl_down(s, o, 64);
  if ((tid & 63) == 0) red[tid >> 6] = s;
  __syncthreads();
  float mu = (red[0] + red[1] + red[2] + red[3]) * (1.f/256.f);
  float d = v - mu;
  float s2 = d * d;
  for (int o = 32; o > 0; o >>= 1) s2 += __shfl_down(s2, o, 64);
  __syncthreads();
  if ((tid & 63) == 0) red[tid >> 6] = s2;
  __syncthreads();
  float var = (red[0] + red[1] + red[2] + red[3]) * (1.f/256.f);
  x[m*256 + tid] = d * rsqrtf(var + 1e-5f) * g[tid] + b[tid];
}

// ---------------------------------------------------------------------------
// q_pool + x1 = q_pool @ l1_w^T + l1_b : one block per n (global, all N at once)
__global__ __launch_bounds__(256) void qpool_x1(const float* __restrict__ q_emb,
    const float* __restrict__ l1_w, const float* __restrict__ l1_b,
    float* __restrict__ x1) {
  int n = blockIdx.x;
  int tid = threadIdx.x;
  __shared__ float pool[256];
  float s = 0.f;
  for (int t = 0; t < 14; ++t) s += q_emb[((size_t)n*14 + t)*256 + tid];
  pool[tid] = s * (1.f/14.f);
  __syncthreads();
  for (int e = tid; e < 600; e += 256) {
    float acc = l1_b[e];
    for (int o = 0; o < 256; ++o) acc += pool[o] * l1_w[(size_t)e*256 + o];
    x1[(size_t)n*600 + e] = acc;
  }
}

// ---------------------------------------------------------------------------
// MLB epilogue: per (local) row m: zf=signed_sqrt(x0*x1); L2-norm; sigmoid(dot)
__global__ __launch_bounds__(256) void mlb_kernel(const float* __restrict__ x0,
    const float* __restrict__ x1, const float* __restrict__ lo_w,
    const float* __restrict__ lo_b, float* __restrict__ out) {
  size_t m = blockIdx.x;     // chunk-local row
  size_t n = m / 100;        // chunk-local image
  int tid = threadIdx.x;
  float z[3] = {0.f, 0.f, 0.f};
  float ss = 0.f;
  int cnt = 0;
  for (int e = tid; e < 600; e += 256) {
    float v = x0[m*600 + e] * x1[n*600 + e];
    float r = (v >= 0.f) ? sqrtf(v) : -sqrtf(-v);
    z[cnt++] = r;
    ss += r * r;
  }
  __shared__ float red[4];
  for (int o = 32; o > 0; o >>= 1) ss += __shfl_down(ss, o, 64);
  if ((tid & 63) == 0) red[tid >> 6] = ss;
  __syncthreads();
  ss = red[0] + red[1] + red[2] + red[3];
  float inv = 1.f / fmaxf(sqrtf(ss), 1e-12f);
  float dot = 0.f;
  cnt = 0;
  for (int e = tid; e < 600; e += 256) dot += z[cnt++] * lo_w[e];
  for (int o = 32; o > 0; o >>= 1) dot += __shfl_down(dot, o, 64);
  __syncthreads();
  if ((tid & 63) == 0) red[tid >> 6] = dot;
  __syncthreads();
  if (tid == 0) {
    float sc = (red[0] + red[1] + red[2] + red[3]) * inv + lo_b[0];
    out[m] = 1.f / (1.f + __expf(-sc));
  }
}

// ---------------------------------------------------------------------------
// block-wide sum over 256 threads (4 waves)
__device__ __forceinline__ float breduce(float v, float* red, int tid) {
  for (int o = 32; o > 0; o >>= 1) v += __shfl_down(v, o, 64);
  if ((tid & 63) == 0) red[tid >> 6] = v;
  __syncthreads();
  float r = red[0] + red[1] + red[2] + red[3];
  __syncthreads();
  return r;
}

// counting module: one block per n (global)
__global__ __launch_bounds__(256) void counter_kernel(
    const float* __restrict__ scores, const float* __restrict__ boxes,
    const float* __restrict__ plw, const float* __restrict__ plc,
    float* __restrict__ pred, float* __restrict__ conf_out) {
  int n = blockIdx.x, tid = threadIdx.x;
  __shared__ float plw_s[8][17], plc_s[8][17];
  __shared__ float sval[128];
  __shared__ int   sidx[128];
  __shared__ float att[36], bx[36][4];
  __shared__ float dist[36][36], scr[36][36], ds2[36][36], sim[36][36];
  __shared__ float rs[36];
  __shared__ float red[4];
  __shared__ float b_f, b_cf;
  __shared__ int   b_i;

  for (int i = tid; i < 136; i += 256) {
    (&plw_s[0][0])[i] = plw[i];
    (&plc_s[0][0])[i] = plc[i];
  }
  if (tid < 128) {
    sval[tid] = (tid < 100) ? scores[(size_t)n*100 + tid] : -1e30f;
    sidx[tid] = tid;
  }
  __syncthreads();

  // bitonic sort, final order: descending value, ties -> lower index first
  for (int k = 2; k <= 128; k <<= 1) {
    for (int j = k >> 1; j > 0; j >>= 1) {
      if (tid < 128) {
        int ixj = tid ^ j;
        if (ixj > tid) {
          float va = sval[tid], vb = sval[ixj];
          int   ia = sidx[tid], ib = sidx[ixj];
          bool a_before_b = (va > vb) || (va == vb && ia < ib);
          bool ascending = ((tid & k) == 0);
          bool doswap = ascending ? !a_before_b : a_before_b;
          if (doswap) { sval[tid] = vb; sval[ixj] = va; sidx[tid] = ib; sidx[ixj] = ia; }
        }
      }
      __syncthreads();
    }
  }

  if (tid < 36) {
    att[tid] = sval[tid];
    const float* bp = boxes + ((size_t)n*100 + sidx[tid])*4;
    bx[tid][0] = bp[0]; bx[tid][1] = bp[1]; bx[tid][2] = bp[2]; bx[tid][3] = bp[3];
  }
  __syncthreads();

  for (int idx = tid; idx < 1296; idx += 256) {
    int i = idx / 36, j = idx % 36;
    float x1a = bx[i][0], y1a = bx[i][1], x2a = bx[i][2], y2a = bx[i][3];
    float x1b = bx[j][0], y1b = bx[j][1], x2b = bx[j][2], y2b = bx[j][3];
    float areaA = fmaxf(x2a - x1a, 0.f) * fmaxf(y2a - y1a, 0.f);
    float areaB = fmaxf(x2b - x1b, 0.f) * fmaxf(y2b - y1b, 0.f);
    float iw = fmaxf(fminf(x2a, x2b) - fmaxf(x1a, x1b), 0.f);
    float ih = fmaxf(fminf(y2a, y2b) - fmaxf(y1a, y1b), 0.f);
    float inter = iw * ih;
    float iou = inter / (areaA + areaB - inter + 1e-12f);
    float dd = 1.f - iou;
    float rel = att[i] * att[j];
    dist[i][j] = dd;
    scr[i][j]  = plin_f(plw_s[0], plc_s[0], rel) * plin_f(plw_s[1], plc_s[1], dd);
    ds2[i][j]  = plin_f(plw_s[3], plc_s[3], rel) * plin_f(plw_s[4], plc_s[4], dd);
  }
  __syncthreads();

  for (int idx = tid; idx < 1296; idx += 256) {
    int b = idx / 36, c = idx % 36;
    float p = plin_f(plw_s[2], plc_s[2], 1.f - fabsf(att[b] - att[c]));
    for (int a = 0; a < 36; ++a)
      p *= plin_f(plw_s[2], plc_s[2], 1.f - fabsf(ds2[a][b] - ds2[a][c]));
    sim[b][c] = p;
  }
  __syncthreads();

  if (tid < 36) {
    float s = 0.f;
    for (int c = 0; c < 36; ++c) s += sim[tid][c];
    rs[tid] = s;
  }
  __syncthreads();

  float p1 = 0.f, p4 = 0.f;
  for (int idx = tid; idx < 1296; idx += 256) {
    int b = idx / 36, c = idx % 36;
    p1 += scr[b][c] / (rs[b] * rs[c]);
    p4 += fabsf(plin_f(plw_s[6], plc_s[6], dist[b][c]) - 0.5f);
  }
  float p2 = 0.f, p3 = 0.f;
  if (tid < 36) {
    p2 = plin_f(plw_s[0], plc_s[0], att[tid]*att[tid]) / rs[tid];
    p3 = fabsf(plin_f(plw_s[5], plc_s[5], att[tid]) - 0.5f);
  }
  float s1 = breduce(p1, red, tid);
  float s2 = breduce(p2, red, tid);
  float s3 = breduce(p3, red, tid);
  float s4 = breduce(p4, red, tid);

  if (tid == 0) {
    float total = sqrtf(s1 + s2 + 1e-20f);
    float cf = plin_f(plw_s[7], plc_s[7], s3 * (1.f/36.f) + s4 * (1.f/1296.f));
    float sc = fminf(fmaxf(total, 0.f), 36.f);
    float fl = floorf(sc);
    int ii = (int)fl; if (ii > 36) ii = 36;
    b_f = sc - fl;
    b_i = ii;
    b_cf = cf;
    conf_out[n] = cf;
  }
  __syncthreads();
  if (tid < 37) {
    int ii = b_i;
    int ir = (ii + 1 > 36) ? 36 : ii + 1;
    float v = ((tid == ii) ? (1.f - b_f) : 0.f) + ((tid == ir) ? b_f : 0.f);
    pred[(size_t)n*37 + tid] = v * b_cf;
  }
}

// ---------------------------------------------------------------------------
extern "C" void kernel_launch(void* const* d_in, const int* in_sizes, int n_in,
                              void* d_out, int out_size, void* d_ws, size_t ws_size,
                              hipStream_t stream) {
  const float* v_emb = (const float*)d_in[0];
  const float* q_emb = (const float*)d_in[1];
  const float* boxes = (const float*)d_in[2];
  const float* Wq    = (const float*)d_in[3];
  const float* bq    = (const float*)d_in[4];
  const float* Wk    = (const float*)d_in[5];
  const float* bk    = (const float*)d_in[6];
  const float* Wv    = (const float*)d_in[7];
  const float* bv    = (const float*)d_in[8];
  const float* in_w  = (const float*)d_in[9];
  const float* in_b  = (const float*)d_in[10];
  const float* out_w = (const float*)d_in[11];
  const float* out_b = (const float*)d_in[12];
  const float* ln_g  = (const float*)d_in[13];
  const float* ln_b  = (const float*)d_in[14];
  const float* l0_w  = (const float*)d_in[15];
  const float* l0_b  = (const float*)d_in[16];
  const float* l1_w  = (const float*)d_in[17];
  const float* l1_b  = (const float*)d_in[18];
  const float* lo_w  = (const float*)d_in[19];
  const float* lo_b  = (const float*)d_in[20];
  const float* pw    = (const float*)d_in[21];

  float* ws = (float*)d_ws;
  // small persistent region (3.25 MB)
  float* plw  = ws + 0;        // 136  (reserve 256)
  float* plc  = ws + 256;      // 136  (reserve 256)
  float* cbuf = ws + 512;      // 768  (reserve 1024-512=768... next at 1280)
  float* A    = ws + 1280;     // 196608
  float* x1   = ws + 197888;   // 614400
  const size_t small_floats = 812544;

  // adaptive chunk size: per-image cost = 100*(768+256+256+600) = 188,000 floats
  size_t avail = (ws_size / 4 > small_floats) ? (ws_size / 4 - small_floats) : 0;
  int NC = 1024;
  while (NC > 16 && (size_t)NC * 188000ull > avail) NC >>= 1;

  float* qkv_c   = ws + small_floats;            // NC*76800
  float* ao_c    = qkv_c   + (size_t)NC * 76800; // NC*25600
  float* inter_c = ao_c    + (size_t)NC * 25600; // NC*25600
  float* x0_c    = inter_c + (size_t)NC * 25600; // NC*60000

  float* out    = (float*)d_out;
  float* scores = out;             // N*R
  float* pred   = out + 102400;    // N*37
  float* conf   = out + 140288;    // N

  prep_plin<<<1, 64, 0, stream>>>(pw, plw, plc);
  fuse_c<<<3, 256, 0, stream>>>(in_w, in_b, bq, bk, bv, cbuf);
  fuse_A<<<768, 256, 0, stream>>>(in_w, Wq, Wk, Wv, A);
  qpool_x1<<<N_, 256, 0, stream>>>(q_emb, l1_w, l1_b, x1);

  for (int n0 = 0; n0 < N_; n0 += NC) {
    const int M = NC * 100;           // rows in this chunk (divisible by 64 for NC>=16)
    const float* vchunk = v_emb + (size_t)n0 * 100 * 256;

    dim3 g1(M / 64, 12);
    gemm_xt<false><<<g1, 256, 0, stream>>>(vchunk, A, cbuf, qkv_c, M, 256, 768);

    attn_kernel<<<NC * H_, 256, 0, stream>>>(qkv_c, ao_c);

    dim3 g2(M / 64, 4);
    gemm_xt<false><<<g2, 256, 0, stream>>>(ao_c, out_w, out_b, inter_c, M, 256, 256);

    ln_kernel<<<M, 256, 0, stream>>>(inter_c, ln_g, ln_b);

    dim3 g3(M / 64, 10);
    gemm_xt<true><<<g3, 256, 0, stream>>>(inter_c, l0_w, l0_b, x0_c, M, 256, 600);

    mlb_kernel<<<M, 256, 0, stream>>>(x0_c, x1 + (size_t)n0 * 600, lo_w, lo_b,
                                      scores + (size_t)n0 * 100);
  }

  counter_kernel<<<N_, 256, 0, stream>>>(scores, boxes, plw, plc, pred, conf);
}

// Round 5
// 1845.857 us; speedup vs baseline: 1.7179x; 1.7179x over previous
//
#include <hip/hip_runtime.h>

// Problem constants
#define N_   1024
#define R_   100
#define D_   256
#define T_   14
#define H_   8
#define DH_  32
#define MM_  600
#define OBJ_ 36

typedef _Float16 f16;
typedef __attribute__((ext_vector_type(8))) _Float16 f16x8;
typedef __attribute__((ext_vector_type(4))) float f32x4;

// fp32 -> (hi, lo) fp16 split: x ≈ hi + lo with ~22-bit combined mantissa
__device__ __forceinline__ void f2h_split(float x, f16& hi, f16& lo) {
  hi = (_Float16)x;
  lo = (_Float16)(x - (float)hi);
}

// async 16B global->LDS
#define GL16(gp, lp) __builtin_amdgcn_global_load_lds( \
    (const __attribute__((address_space(1))) void*)(gp), \
    (__attribute__((address_space(3))) void*)(lp), 16, 0, 0)

// ---------------------------------------------------------------------------
// piecewise-linear map helper: tables (w, cs) each 17 entries per row
__device__ __forceinline__ float plin_f(const float* __restrict__ w,
                                        const float* __restrict__ cs, float x) {
  float xc = fminf(fmaxf(x, 0.f), 1.f);
  float y  = 16.f * xc;
  float fy = floorf(y);
  int   i  = (int)fy;              // 0..16
  float f  = y - fy;
  int   ip = i + 1; if (ip > 16) ip = 16;
  return cs[i] + f * w[ip];
}

// ---------------------------------------------------------------------------
__global__ void prep_plin(const float* __restrict__ pw, float* __restrict__ plw,
                          float* __restrict__ plc) {
  int p = threadIdx.x;
  if (p < 8) {
    float w[17];
    float sum = 0.f;
    w[0] = 0.f;
    for (int k = 1; k < 17; ++k) { w[k] = fabsf(pw[p*17 + k]); sum += w[k]; }
    float inv = 1.f / sum;
    float c = 0.f;
    for (int k = 0; k < 17; ++k) {
      float wk = w[k] * inv;
      c += wk;
      plw[p*17 + k] = wk;
      plc[p*17 + k] = c;
    }
  }
}

// ---------------------------------------------------------------------------
// fused QKV bias: c[i] = in_b[i] + sum_o in_w[i][o]*b{q,k,v}[o]
__global__ void fuse_c(const float* __restrict__ in_w, const float* __restrict__ in_b,
                       const float* __restrict__ bq, const float* __restrict__ bk,
                       const float* __restrict__ bv, float* __restrict__ c) {
  int i = blockIdx.x * blockDim.x + threadIdx.x;
  if (i < 768) {
    const float* bsel = (i < 256) ? bq : ((i < 512) ? bk : bv);
    float acc = in_b[i];
    for (int o = 0; o < 256; ++o) acc += in_w[(size_t)i*256 + o] * bsel[o];
    c[i] = acc;
  }
}

// fused QKV weight (split fp16 out): A[i][j] = sum_o in_w[i][o] * W{q,k,v}[o][j]
__global__ __launch_bounds__(256) void fuse_A(const float* __restrict__ in_w,
    const float* __restrict__ Wq, const float* __restrict__ Wk,
    const float* __restrict__ Wv, f16* __restrict__ Ahi, f16* __restrict__ Alo) {
  int i = blockIdx.x;        // 0..767
  int j = threadIdx.x;       // 0..255
  const float* Wsel = (i < 256) ? Wq : ((i < 512) ? Wk : Wv);
  __shared__ float row[256];
  row[j] = in_w[(size_t)i*256 + j];
  __syncthreads();
  float acc = 0.f;
  for (int o = 0; o < 256; ++o) acc += row[o] * Wsel[(size_t)o*256 + j];
  f16 h, l; f2h_split(acc, h, l);
  Ahi[(size_t)i*256 + j] = h;
  Alo[(size_t)i*256 + j] = l;
}

// generic fp32 -> split fp16 conversion, 4 elems/thread
__global__ __launch_bounds__(256) void split_vec(const float* __restrict__ in,
    f16* __restrict__ hi, f16* __restrict__ lo, int n4) {
  int i = blockIdx.x * blockDim.x + threadIdx.x;
  if (i < n4) {
    float4 v = ((const float4*)in)[i];
    union { f16 h[4]; ushort4 u; } H, L;
    f2h_split(v.x, H.h[0], L.h[0]);
    f2h_split(v.y, H.h[1], L.h[1]);
    f2h_split(v.z, H.h[2], L.h[2]);
    f2h_split(v.w, H.h[3], L.h[3]);
    ((ushort4*)hi)[i] = H.u;
    ((ushort4*)lo)[i] = L.u;
  }
}

// l0_w (600x256) -> split fp16 padded to 640x256 (zero rows beyond 600)
__global__ __launch_bounds__(256) void conv_l0w(const float* __restrict__ w,
    f16* __restrict__ hi, f16* __restrict__ lo) {
  int o = blockIdx.x;        // 0..639
  int j = threadIdx.x;       // 0..255
  f16 h = (f16)0.f, l = (f16)0.f;
  if (o < 600) f2h_split(w[(size_t)o*256 + j], h, l);
  hi[(size_t)o*256 + j] = h;
  lo[(size_t)o*256 + j] = l;
}

// ---------------------------------------------------------------------------
// split-fp16 MFMA GEMM (fp32-accurate): C[m][o] = sum_k X[m][k]*W[o][k] + bias[o]
// X = Xhi+Xlo, W = Whi+Wlo (f16, row-major, K=256). C fp32, stride Oreal.
// X*W ≈ Xhi*Whi + Xhi*Wlo + Xlo*Whi  (lo*lo dropped, ~2^-22 rel)
// Tile 128x128, BK=32, 256 thr (4 waves), 4x4 16x16x32 frags/wave, 48 MFMA/k-step.
template<bool BOUND>
__global__ __launch_bounds__(256) void gemm_f16s(
    const f16* __restrict__ Xhi, const f16* __restrict__ Xlo,
    const f16* __restrict__ Whi, const f16* __restrict__ Wlo,
    const float* __restrict__ bias, float* __restrict__ C, int Oreal) {
  __shared__ f16 XsH[128 * 32];
  __shared__ f16 XsL[128 * 32];
  __shared__ f16 WsH[128 * 32];
  __shared__ f16 WsL[128 * 32];
  const int tid  = threadIdx.x;
  const int wave = tid >> 6, lane = tid & 63;
  const int bm = blockIdx.x * 128, bn = blockIdx.y * 128;
  const int wm = (wave & 1) * 64, wn = (wave >> 1) * 64;
  const int col = lane & 15, quad = lane >> 4;

  // staging: lane s covers 16B; issue0 rows 0..63, issue1 rows 64..127
  const int s = wave * 64 + lane;
  const int r0 = s >> 2,         cseg = (s & 3) * 8;
  const int r1 = (s + 256) >> 2;
  const size_t o0 = (size_t)(bm + r0) * 256 + cseg;
  const size_t o1 = (size_t)(bm + r1) * 256 + cseg;
  const size_t p0 = (size_t)(bn + r0) * 256 + cseg;
  const size_t p1 = (size_t)(bn + r1) * 256 + cseg;
  char* XHB = (char*)XsH + wave * 1024;
  char* XLB = (char*)XsL + wave * 1024;
  char* WHB = (char*)WsH + wave * 1024;
  char* WLB = (char*)WsL + wave * 1024;

  f32x4 acc[4][4] = {};

  for (int k0 = 0; k0 < 256; k0 += 32) {
    GL16(Xhi + o0 + k0, XHB);
    GL16(Xhi + o1 + k0, XHB + 4096);
    GL16(Xlo + o0 + k0, XLB);
    GL16(Xlo + o1 + k0, XLB + 4096);
    GL16(Whi + p0 + k0, WHB);
    GL16(Whi + p1 + k0, WHB + 4096);
    GL16(Wlo + p0 + k0, WLB);
    GL16(Wlo + p1 + k0, WLB + 4096);
    __syncthreads();

    f16x8 ah[4], al[4], bh[4], bl[4];
#pragma unroll
    for (int i = 0; i < 4; ++i) {
      int ro = (wm + i*16 + col) * 32 + quad * 8;
      ah[i] = *(const f16x8*)(XsH + ro);
      al[i] = *(const f16x8*)(XsL + ro);
    }
#pragma unroll
    for (int j = 0; j < 4; ++j) {
      int ro = (wn + j*16 + col) * 32 + quad * 8;
      bh[j] = *(const f16x8*)(WsH + ro);
      bl[j] = *(const f16x8*)(WsL + ro);
    }
#pragma unroll
    for (int i = 0; i < 4; ++i)
#pragma unroll
      for (int j = 0; j < 4; ++j) {
        acc[i][j] = __builtin_amdgcn_mfma_f32_16x16x32_f16(al[i], bh[j], acc[i][j], 0, 0, 0);
        acc[i][j] = __builtin_amdgcn_mfma_f32_16x16x32_f16(ah[i], bl[j], acc[i][j], 0, 0, 0);
        acc[i][j] = __builtin_amdgcn_mfma_f32_16x16x32_f16(ah[i], bh[j], acc[i][j], 0, 0, 0);
      }
    __syncthreads();
  }

  // epilogue: C/D layout col=lane&15, row=quad*4+reg
#pragma unroll
  for (int j = 0; j < 4; ++j) {
    int o = bn + wn + j*16 + col;
    if (BOUND && o >= Oreal) continue;
    float bo = bias[o];
#pragma unroll
    for (int i = 0; i < 4; ++i) {
#pragma unroll
      for (int r = 0; r < 4; ++r) {
        int m = bm + wm + i*16 + quad*4 + r;
        C[(size_t)m * Oreal + o] = acc[i][j][r] + bo;
      }
    }
  }
}

// ---------------------------------------------------------------------------
// attention: one block per (local n, h).  qkv layout (nc, r, 768): q|k|v each 256.
// fp32 compute; writes ao as split fp16
__global__ __launch_bounds__(256) void attn_kernel(const float* __restrict__ qkv,
    f16* __restrict__ aohi, f16* __restrict__ aolo) {
  const int n = blockIdx.x >> 3;   // chunk-local
  const int h = blockIdx.x & 7;
  __shared__ float qs[100][33], ks[100][33], vs[100][33];
  __shared__ float at[25][100];
  const float scale = 0.17677669529663687f;  // 1/sqrt(32)
  const int tid = threadIdx.x;
  const float* base = qkv + (size_t)n * 100 * 768;
  for (int idx = tid; idx < 3200; idx += 256) {
    int r = idx >> 5, d = idx & 31;
    const float* p = base + (size_t)r*768 + h*32 + d;
    qs[r][d] = p[0];
    ks[r][d] = p[256];
    vs[r][d] = p[512];
  }
  __syncthreads();
  for (int c0 = 0; c0 < 100; c0 += 25) {
    for (int idx = tid; idx < 2500; idx += 256) {
      int i = idx / 100, j = idx % 100;
      float acc = 0.f;
#pragma unroll
      for (int k2 = 0; k2 < 32; ++k2) acc += qs[c0 + i][k2] * ks[j][k2];
      at[i][j] = acc * scale;
    }
    __syncthreads();
    if (tid < 25) {
      float m = -1e30f;
      for (int j = 0; j < 100; ++j) m = fmaxf(m, at[tid][j]);
      float s = 0.f;
      for (int j = 0; j < 100; ++j) { float e = __expf(at[tid][j] - m); at[tid][j] = e; s += e; }
      float inv = 1.f / s;
      for (int j = 0; j < 100; ++j) at[tid][j] *= inv;
    }
    __syncthreads();
    for (int idx = tid; idx < 800; idx += 256) {
      int r = idx >> 5, d = idx & 31;
      float acc = 0.f;
      for (int j = 0; j < 100; ++j) acc += at[r][j] * vs[j][d];
      size_t oidx = ((size_t)n*100 + c0 + r)*256 + h*32 + d;
      f16 hh, ll; f2h_split(acc, hh, ll);
      aohi[oidx] = hh;
      aolo[oidx] = ll;
    }
    __syncthreads();
  }
}

// ---------------------------------------------------------------------------
// layernorm: read fp32, write split fp16: one block (256 thr) per row of 256
__global__ __launch_bounds__(256) void ln_kernel(const float* __restrict__ x,
    const float* __restrict__ g, const float* __restrict__ b,
    f16* __restrict__ ohi, f16* __restrict__ olo) {
  size_t m = blockIdx.x;
  int tid = threadIdx.x;
  float v = x[m*256 + tid];
  __shared__ float red[4];
  float s = v;
  for (int o = 32; o > 0; o >>= 1) s += __shfl_down(s, o, 64);
  if ((tid & 63) == 0) red[tid >> 6] = s;
  __syncthreads();
  float mu = (red[0] + red[1] + red[2] + red[3]) * (1.f/256.f);
  float d = v - mu;
  float s2 = d * d;
  for (int o = 32; o > 0; o >>= 1) s2 += __shfl_down(s2, o, 64);
  __syncthreads();
  if ((tid & 63) == 0) red[tid >> 6] = s2;
  __syncthreads();
  float var = (red[0] + red[1] + red[2] + red[3]) * (1.f/256.f);
  float r = d * rsqrtf(var + 1e-5f) * g[tid] + b[tid];
  f16 hh, ll; f2h_split(r, hh, ll);
  ohi[m*256 + tid] = hh;
  olo[m*256 + tid] = ll;
}

// ---------------------------------------------------------------------------
// q_pool + x1 = q_pool @ l1_w^T + l1_b : one block per n (global)
__global__ __launch_bounds__(256) void qpool_x1(const float* __restrict__ q_emb,
    const float* __restrict__ l1_w, const float* __restrict__ l1_b,
    float* __restrict__ x1) {
  int n = blockIdx.x;
  int tid = threadIdx.x;
  __shared__ float pool[256];
  float s = 0.f;
  for (int t = 0; t < 14; ++t) s += q_emb[((size_t)n*14 + t)*256 + tid];
  pool[tid] = s * (1.f/14.f);
  __syncthreads();
  for (int e = tid; e < 600; e += 256) {
    float acc = l1_b[e];
    for (int o = 0; o < 256; ++o) acc += pool[o] * l1_w[(size_t)e*256 + o];
    x1[(size_t)n*600 + e] = acc;
  }
}

// ---------------------------------------------------------------------------
// MLB epilogue
__global__ __launch_bounds__(256) void mlb_kernel(const float* __restrict__ x0,
    const float* __restrict__ x1, const float* __restrict__ lo_w,
    const float* __restrict__ lo_b, float* __restrict__ out) {
  size_t m = blockIdx.x;     // chunk-local row
  size_t n = m / 100;        // chunk-local image
  int tid = threadIdx.x;
  float z[3] = {0.f, 0.f, 0.f};
  float ss = 0.f;
  int cnt = 0;
  for (int e = tid; e < 600; e += 256) {
    float v = x0[m*600 + e] * x1[n*600 + e];
    float r = (v >= 0.f) ? sqrtf(v) : -sqrtf(-v);
    z[cnt++] = r;
    ss += r * r;
  }
  __shared__ float red[4];
  for (int o = 32; o > 0; o >>= 1) ss += __shfl_down(ss, o, 64);
  if ((tid & 63) == 0) red[tid >> 6] = ss;
  __syncthreads();
  ss = red[0] + red[1] + red[2] + red[3];
  float inv = 1.f / fmaxf(sqrtf(ss), 1e-12f);
  float dot = 0.f;
  cnt = 0;
  for (int e = tid; e < 600; e += 256) dot += z[cnt++] * lo_w[e];
  for (int o = 32; o > 0; o >>= 1) dot += __shfl_down(dot, o, 64);
  __syncthreads();
  if ((tid & 63) == 0) red[tid >> 6] = dot;
  __syncthreads();
  if (tid == 0) {
    float sc = (red[0] + red[1] + red[2] + red[3]) * inv + lo_b[0];
    out[m] = 1.f / (1.f + __expf(-sc));
  }
}

// ---------------------------------------------------------------------------
__device__ __forceinline__ float breduce(float v, float* red, int tid) {
  for (int o = 32; o > 0; o >>= 1) v += __shfl_down(v, o, 64);
  if ((tid & 63) == 0) red[tid >> 6] = v;
  __syncthreads();
  float r = red[0] + red[1] + red[2] + red[3];
  __syncthreads();
  return r;
}

// counting module: one block per n (global)
__global__ __launch_bounds__(256) void counter_kernel(
    const float* __restrict__ scores, const float* __restrict__ boxes,
    const float* __restrict__ plw, const float* __restrict__ plc,
    float* __restrict__ pred, float* __restrict__ conf_out) {
  int n = blockIdx.x, tid = threadIdx.x;
  __shared__ float plw_s[8][17], plc_s[8][17];
  __shared__ float sval[128];
  __shared__ int   sidx[128];
  __shared__ float att[36], bx[36][4];
  __shared__ float dist[36][36], scr[36][36], ds2[36][36], sim[36][36];
  __shared__ float rs[36];
  __shared__ float red[4];
  __shared__ float b_f, b_cf;
  __shared__ int   b_i;

  for (int i = tid; i < 136; i += 256) {
    (&plw_s[0][0])[i] = plw[i];
    (&plc_s[0][0])[i] = plc[i];
  }
  if (tid < 128) {
    sval[tid] = (tid < 100) ? scores[(size_t)n*100 + tid] : -1e30f;
    sidx[tid] = tid;
  }
  __syncthreads();

  for (int k = 2; k <= 128; k <<= 1) {
    for (int j = k >> 1; j > 0; j >>= 1) {
      if (tid < 128) {
        int ixj = tid ^ j;
        if (ixj > tid) {
          float va = sval[tid], vb = sval[ixj];
          int   ia = sidx[tid], ib = sidx[ixj];
          bool a_before_b = (va > vb) || (va == vb && ia < ib);
          bool ascending = ((tid & k) == 0);
          bool doswap = ascending ? !a_before_b : a_before_b;
          if (doswap) { sval[tid] = vb; sval[ixj] = va; sidx[tid] = ib; sidx[ixj] = ia; }
        }
      }
      __syncthreads();
    }
  }

  if (tid < 36) {
    att[tid] = sval[tid];
    const float* bp = boxes + ((size_t)n*100 + sidx[tid])*4;
    bx[tid][0] = bp[0]; bx[tid][1] = bp[1]; bx[tid][2] = bp[2]; bx[tid][3] = bp[3];
  }
  __syncthreads();

  for (int idx = tid; idx < 1296; idx += 256) {
    int i = idx / 36, j = idx % 36;
    float x1a = bx[i][0], y1a = bx[i][1], x2a = bx[i][2], y2a = bx[i][3];
    float x1b = bx[j][0], y1b = bx[j][1], x2b = bx[j][2], y2b = bx[j][3];
    float areaA = fmaxf(x2a - x1a, 0.f) * fmaxf(y2a - y1a, 0.f);
    float areaB = fmaxf(x2b - x1b, 0.f) * fmaxf(y2b - y1b, 0.f);
    float iw = fmaxf(fminf(x2a, x2b) - fmaxf(x1a, x1b), 0.f);
    float ih = fmaxf(fminf(y2a, y2b) - fmaxf(y1a, y1b), 0.f);
    float inter = iw * ih;
    float iou = inter / (areaA + areaB - inter + 1e-12f);
    float dd = 1.f - iou;
    float rel = att[i] * att[j];
    dist[i][j] = dd;
    scr[i][j]  = plin_f(plw_s[0], plc_s[0], rel) * plin_f(plw_s[1], plc_s[1], dd);
    ds2[i][j]  = plin_f(plw_s[3], plc_s[3], rel) * plin_f(plw_s[4], plc_s[4], dd);
  }
  __syncthreads();

  for (int idx = tid; idx < 1296; idx += 256) {
    int b = idx / 36, c = idx % 36;
    float p = plin_f(plw_s[2], plc_s[2], 1.f - fabsf(att[b] - att[c]));
    for (int a = 0; a < 36; ++a)
      p *= plin_f(plw_s[2], plc_s[2], 1.f - fabsf(ds2[a][b] - ds2[a][c]));
    sim[b][c] = p;
  }
  __syncthreads();

  if (tid < 36) {
    float s = 0.f;
    for (int c = 0; c < 36; ++c) s += sim[tid][c];
    rs[tid] = s;
  }
  __syncthreads();

  float p1 = 0.f, p4 = 0.f;
  for (int idx = tid; idx < 1296; idx += 256) {
    int b = idx / 36, c = idx % 36;
    p1 += scr[b][c] / (rs[b] * rs[c]);
    p4 += fabsf(plin_f(plw_s[6], plc_s[6], dist[b][c]) - 0.5f);
  }
  float p2 = 0.f, p3 = 0.f;
  if (tid < 36) {
    p2 = plin_f(plw_s[0], plc_s[0], att[tid]*att[tid]) / rs[tid];
    p3 = fabsf(plin_f(plw_s[5], plc_s[5], att[tid]) - 0.5f);
  }
  float s1 = breduce(p1, red, tid);
  float s2 = breduce(p2, red, tid);
  float s3 = breduce(p3, red, tid);
  float s4 = breduce(p4, red, tid);

  if (tid == 0) {
    float total = sqrtf(s1 + s2 + 1e-20f);
    float cf = plin_f(plw_s[7], plc_s[7], s3 * (1.f/36.f) + s4 * (1.f/1296.f));
    float sc = fminf(fmaxf(total, 0.f), 36.f);
    float fl = floorf(sc);
    int ii = (int)fl; if (ii > 36) ii = 36;
    b_f = sc - fl;
    b_i = ii;
    b_cf = cf;
    conf_out[n] = cf;
  }
  __syncthreads();
  if (tid < 37) {
    int ii = b_i;
    int ir = (ii + 1 > 36) ? 36 : ii + 1;
    float v = ((tid == ii) ? (1.f - b_f) : 0.f) + ((tid == ir) ? b_f : 0.f);
    pred[(size_t)n*37 + tid] = v * b_cf;
  }
}

// ---------------------------------------------------------------------------
extern "C" void kernel_launch(void* const* d_in, const int* in_sizes, int n_in,
                              void* d_out, int out_size, void* d_ws, size_t ws_size,
                              hipStream_t stream) {
  const float* v_emb = (const float*)d_in[0];
  const float* q_emb = (const float*)d_in[1];
  const float* boxes = (const float*)d_in[2];
  const float* Wq    = (const float*)d_in[3];
  const float* bq    = (const float*)d_in[4];
  const float* Wk    = (const float*)d_in[5];
  const float* bk    = (const float*)d_in[6];
  const float* Wv    = (const float*)d_in[7];
  const float* bv    = (const float*)d_in[8];
  const float* in_w  = (const float*)d_in[9];
  const float* in_b  = (const float*)d_in[10];
  const float* out_w = (const float*)d_in[11];
  const float* out_b = (const float*)d_in[12];
  const float* ln_g  = (const float*)d_in[13];
  const float* ln_b  = (const float*)d_in[14];
  const float* l0_w  = (const float*)d_in[15];
  const float* l0_b  = (const float*)d_in[16];
  const float* l1_w  = (const float*)d_in[17];
  const float* l1_b  = (const float*)d_in[18];
  const float* lo_w  = (const float*)d_in[19];
  const float* lo_b  = (const float*)d_in[20];
  const float* pw    = (const float*)d_in[21];

  float* ws = (float*)d_ws;
  // persistent fp32 region
  float* plw   = ws + 0;        // 136 (reserve 256)
  float* plc   = ws + 256;      // 136 (reserve 256)
  float* cbuf  = ws + 512;      // 768
  float* x1    = ws + 1280;     // 614400 -> 615680
  // persistent f16 region (element offsets within hb)
  f16* hb = (f16*)(ws + 615680);
  f16* A_hi    = hb + 0;         // 768*256 = 196608
  f16* A_lo    = hb + 196608;
  f16* outw_hi = hb + 393216;    // 256*256 = 65536
  f16* outw_lo = hb + 458752;
  f16* l0w_hi  = hb + 524288;    // 640*256 = 163840
  f16* l0w_lo  = hb + 688128;
  f16* v_hi    = hb + 851968;    // 102400*256 = 26214400
  f16* v_lo    = hb + 27066368;  // end: 53280768 f16 = 26640384 float slots
  const size_t small_floats = 615680 + 26640384;   // 27,256,064 floats (~109 MB)

  // per-image chunk cost (floats): qkv 76800 + inter 25600 + x0 60000
  //   + f16 halves (ao_hi/lo + int_hi/lo = 102400 halves = 51200 floats) = 213600
  size_t avail = (ws_size / 4 > small_floats) ? (ws_size / 4 - small_floats) : 0;
  int NC = 1024;
  while (NC > 32 && (size_t)NC * 213600ull > avail) NC >>= 1;

  float* qkv_c   = ws + small_floats;                 // NC*76800
  float* inter_c = qkv_c   + (size_t)NC * 76800;      // NC*25600
  float* x0_c    = inter_c + (size_t)NC * 25600;      // NC*60000
  f16* ao_hi  = (f16*)(x0_c + (size_t)NC * 60000);    // NC*25600
  f16* ao_lo  = ao_hi + (size_t)NC * 25600;
  f16* int_hi = ao_lo + (size_t)NC * 25600;
  f16* int_lo = int_hi + (size_t)NC * 25600;

  float* out    = (float*)d_out;
  float* scores = out;             // N*R
  float* pred   = out + 102400;    // N*37
  float* conf   = out + 140288;    // N

  prep_plin<<<1, 64, 0, stream>>>(pw, plw, plc);
  fuse_c<<<3, 256, 0, stream>>>(in_w, in_b, bq, bk, bv, cbuf);
  fuse_A<<<768, 256, 0, stream>>>(in_w, Wq, Wk, Wv, A_hi, A_lo);
  split_vec<<<(65536/4 + 255)/256, 256, 0, stream>>>(out_w, outw_hi, outw_lo, 65536/4);
  conv_l0w<<<640, 256, 0, stream>>>(l0_w, l0w_hi, l0w_lo);
  split_vec<<<(26214400/4 + 255)/256, 256, 0, stream>>>(v_emb, v_hi, v_lo, 26214400/4);
  qpool_x1<<<N_, 256, 0, stream>>>(q_emb, l1_w, l1_b, x1);

  for (int n0 = 0; n0 < N_; n0 += NC) {
    const int M = NC * 100;           // divisible by 128 for NC>=32
    const size_t voff = (size_t)n0 * 100 * 256;

    dim3 g1(M / 128, 6);   // O=768
    gemm_f16s<false><<<g1, 256, 0, stream>>>(v_hi + voff, v_lo + voff,
                                             A_hi, A_lo, cbuf, qkv_c, 768);

    attn_kernel<<<NC * H_, 256, 0, stream>>>(qkv_c, ao_hi, ao_lo);

    dim3 g2(M / 128, 2);   // O=256
    gemm_f16s<false><<<g2, 256, 0, stream>>>(ao_hi, ao_lo, outw_hi, outw_lo,
                                             out_b, inter_c, 256);

    ln_kernel<<<M, 256, 0, stream>>>(inter_c, ln_g, ln_b, int_hi, int_lo);

    dim3 g3(M / 128, 5);   // Opad=640, Oreal=600
    gemm_f16s<true><<<g3, 256, 0, stream>>>(int_hi, int_lo, l0w_hi, l0w_lo,
                                            l0_b, x0_c, 600);

    mlb_kernel<<<M, 256, 0, stream>>>(x0_c, x1 + (size_t)n0 * 600, lo_w, lo_b,
                                      scores + (size_t)n0 * 100);
  }

  counter_kernel<<<N_, 256, 0, stream>>>(scores, boxes, plw, plc, pred, conf);
}

// Round 6
// 1332.918 us; speedup vs baseline: 2.3791x; 1.3848x over previous
//
#include <hip/hip_runtime.h>

// Problem constants
#define N_   1024
#define R_   100
#define D_   256
#define T_   14
#define H_   8
#define DH_  32
#define MM_  600
#define OBJ_ 36

typedef _Float16 f16;
typedef __attribute__((ext_vector_type(8))) _Float16 f16x8;
typedef __attribute__((ext_vector_type(4))) float f32x4;

// fp32 -> (hi, lo) fp16 split: x ≈ hi + lo with ~22-bit combined mantissa
__device__ __forceinline__ void f2h_split(float x, f16& hi, f16& lo) {
  hi = (_Float16)x;
  lo = (_Float16)(x - (float)hi);
}

// async 16B global->LDS
#define GL16(gp, lp) __builtin_amdgcn_global_load_lds( \
    (const __attribute__((address_space(1))) void*)(gp), \
    (__attribute__((address_space(3))) void*)(lp), 16, 0, 0)

// ---------------------------------------------------------------------------
// piecewise-linear map helper: tables (w, cs) each 17 entries per row
__device__ __forceinline__ float plin_f(const float* __restrict__ w,
                                        const float* __restrict__ cs, float x) {
  float xc = fminf(fmaxf(x, 0.f), 1.f);
  float y  = 16.f * xc;
  float fy = floorf(y);
  int   i  = (int)fy;              // 0..16
  float f  = y - fy;
  int   ip = i + 1; if (ip > 16) ip = 16;
  return cs[i] + f * w[ip];
}

// ---------------------------------------------------------------------------
__global__ void prep_plin(const float* __restrict__ pw, float* __restrict__ plw,
                          float* __restrict__ plc) {
  int p = threadIdx.x;
  if (p < 8) {
    float w[17];
    float sum = 0.f;
    w[0] = 0.f;
    for (int k = 1; k < 17; ++k) { w[k] = fabsf(pw[p*17 + k]); sum += w[k]; }
    float inv = 1.f / sum;
    float c = 0.f;
    for (int k = 0; k < 17; ++k) {
      float wk = w[k] * inv;
      c += wk;
      plw[p*17 + k] = wk;
      plc[p*17 + k] = c;
    }
  }
}

// ---------------------------------------------------------------------------
// fused QKV bias: c[i] = in_b[i] + sum_o in_w[i][o]*b{q,k,v}[o]
__global__ void fuse_c(const float* __restrict__ in_w, const float* __restrict__ in_b,
                       const float* __restrict__ bq, const float* __restrict__ bk,
                       const float* __restrict__ bv, float* __restrict__ c) {
  int i = blockIdx.x * blockDim.x + threadIdx.x;
  if (i < 768) {
    const float* bsel = (i < 256) ? bq : ((i < 512) ? bk : bv);
    float acc = in_b[i];
    for (int o = 0; o < 256; ++o) acc += in_w[(size_t)i*256 + o] * bsel[o];
    c[i] = acc;
  }
}

// fused QKV weight (split fp16 out): A[i][j] = sum_o in_w[i][o] * W{q,k,v}[o][j]
__global__ __launch_bounds__(256) void fuse_A(const float* __restrict__ in_w,
    const float* __restrict__ Wq, const float* __restrict__ Wk,
    const float* __restrict__ Wv, f16* __restrict__ Ahi, f16* __restrict__ Alo) {
  int i = blockIdx.x;        // 0..767
  int j = threadIdx.x;       // 0..255
  const float* Wsel = (i < 256) ? Wq : ((i < 512) ? Wk : Wv);
  __shared__ float row[256];
  row[j] = in_w[(size_t)i*256 + j];
  __syncthreads();
  float acc = 0.f;
  for (int o = 0; o < 256; ++o) acc += row[o] * Wsel[(size_t)o*256 + j];
  f16 h, l; f2h_split(acc, h, l);
  Ahi[(size_t)i*256 + j] = h;
  Alo[(size_t)i*256 + j] = l;
}

// generic fp32 -> split fp16 conversion, 4 elems/thread
__global__ __launch_bounds__(256) void split_vec(const float* __restrict__ in,
    f16* __restrict__ hi, f16* __restrict__ lo, int n4) {
  int i = blockIdx.x * blockDim.x + threadIdx.x;
  if (i < n4) {
    float4 v = ((const float4*)in)[i];
    union { f16 h[4]; ushort4 u; } H, L;
    f2h_split(v.x, H.h[0], L.h[0]);
    f2h_split(v.y, H.h[1], L.h[1]);
    f2h_split(v.z, H.h[2], L.h[2]);
    f2h_split(v.w, H.h[3], L.h[3]);
    ((ushort4*)hi)[i] = H.u;
    ((ushort4*)lo)[i] = L.u;
  }
}

// l0_w (600x256) -> split fp16 padded to 640x256 (zero rows beyond 600)
__global__ __launch_bounds__(256) void conv_l0w(const float* __restrict__ w,
    f16* __restrict__ hi, f16* __restrict__ lo) {
  int o = blockIdx.x;        // 0..639
  int j = threadIdx.x;       // 0..255
  f16 h = (f16)0.f, l = (f16)0.f;
  if (o < 600) f2h_split(w[(size_t)o*256 + j], h, l);
  hi[(size_t)o*256 + j] = h;
  lo[(size_t)o*256 + j] = l;
}

// ---------------------------------------------------------------------------
// split-fp16 MFMA GEMM (fp32-accurate): C[m][o] = sum_k X[m][k]*W[o][k] + bias[o]
// X = Xhi+Xlo, W = Whi+Wlo (f16, row-major, K=256). C fp32, stride Oreal.
// X*W ≈ Xhi*Whi + Xhi*Wlo + Xlo*Whi  (lo*lo dropped, ~2^-22 rel)
// Tile 128x128, BK=32, 256 thr (4 waves), 4x4 16x16x32 frags/wave, 48 MFMA/k-step.
template<bool BOUND>
__global__ __launch_bounds__(256) void gemm_f16s(
    const f16* __restrict__ Xhi, const f16* __restrict__ Xlo,
    const f16* __restrict__ Whi, const f16* __restrict__ Wlo,
    const float* __restrict__ bias, float* __restrict__ C, int Oreal) {
  __shared__ f16 XsH[128 * 32];
  __shared__ f16 XsL[128 * 32];
  __shared__ f16 WsH[128 * 32];
  __shared__ f16 WsL[128 * 32];
  const int tid  = threadIdx.x;
  const int wave = tid >> 6, lane = tid & 63;
  const int bm = blockIdx.x * 128, bn = blockIdx.y * 128;
  const int wm = (wave & 1) * 64, wn = (wave >> 1) * 64;
  const int col = lane & 15, quad = lane >> 4;

  // staging: lane s covers 16B; issue0 rows 0..63, issue1 rows 64..127
  const int s = wave * 64 + lane;
  const int r0 = s >> 2,         cseg = (s & 3) * 8;
  const int r1 = (s + 256) >> 2;
  const size_t o0 = (size_t)(bm + r0) * 256 + cseg;
  const size_t o1 = (size_t)(bm + r1) * 256 + cseg;
  const size_t p0 = (size_t)(bn + r0) * 256 + cseg;
  const size_t p1 = (size_t)(bn + r1) * 256 + cseg;
  char* XHB = (char*)XsH + wave * 1024;
  char* XLB = (char*)XsL + wave * 1024;
  char* WHB = (char*)WsH + wave * 1024;
  char* WLB = (char*)WsL + wave * 1024;

  f32x4 acc[4][4] = {};

  for (int k0 = 0; k0 < 256; k0 += 32) {
    GL16(Xhi + o0 + k0, XHB);
    GL16(Xhi + o1 + k0, XHB + 4096);
    GL16(Xlo + o0 + k0, XLB);
    GL16(Xlo + o1 + k0, XLB + 4096);
    GL16(Whi + p0 + k0, WHB);
    GL16(Whi + p1 + k0, WHB + 4096);
    GL16(Wlo + p0 + k0, WLB);
    GL16(Wlo + p1 + k0, WLB + 4096);
    __syncthreads();

    f16x8 ah[4], al[4], bh[4], bl[4];
#pragma unroll
    for (int i = 0; i < 4; ++i) {
      int ro = (wm + i*16 + col) * 32 + quad * 8;
      ah[i] = *(const f16x8*)(XsH + ro);
      al[i] = *(const f16x8*)(XsL + ro);
    }
#pragma unroll
    for (int j = 0; j < 4; ++j) {
      int ro = (wn + j*16 + col) * 32 + quad * 8;
      bh[j] = *(const f16x8*)(WsH + ro);
      bl[j] = *(const f16x8*)(WsL + ro);
    }
#pragma unroll
    for (int i = 0; i < 4; ++i)
#pragma unroll
      for (int j = 0; j < 4; ++j) {
        acc[i][j] = __builtin_amdgcn_mfma_f32_16x16x32_f16(al[i], bh[j], acc[i][j], 0, 0, 0);
        acc[i][j] = __builtin_amdgcn_mfma_f32_16x16x32_f16(ah[i], bl[j], acc[i][j], 0, 0, 0);
        acc[i][j] = __builtin_amdgcn_mfma_f32_16x16x32_f16(ah[i], bh[j], acc[i][j], 0, 0, 0);
      }
    __syncthreads();
  }

  // epilogue: C/D layout col=lane&15, row=quad*4+reg
#pragma unroll
  for (int j = 0; j < 4; ++j) {
    int o = bn + wn + j*16 + col;
    if (BOUND && o >= Oreal) continue;
    float bo = bias[o];
#pragma unroll
    for (int i = 0; i < 4; ++i) {
#pragma unroll
      for (int r = 0; r < 4; ++r) {
        int m = bm + wm + i*16 + quad*4 + r;
        C[(size_t)m * Oreal + o] = acc[i][j][r] + bo;
      }
    }
  }
}

// ---------------------------------------------------------------------------
// MFMA attention: one block per (local n, h). qkv (nc,100,768) fp32: q|k|v.
// S = scale*Q K^T via split-fp16 MFMA (fp32-accurate), fp32 softmax in LDS,
// O = P V via split-fp16 MFMA. Writes ao as split fp16.
// Tiles: M,N padded 100->112 (7x16). PV K-dim padded 112->128 with zeroed frags.
__global__ __launch_bounds__(256) void attn_mfma(const float* __restrict__ qkv,
    f16* __restrict__ aohi, f16* __restrict__ aolo) {
  const int n = blockIdx.x >> 3;
  const int h = blockIdx.x & 7;
  __shared__ f16 KH[112*32], KL[112*32];      // K rows (split)
  __shared__ f16 VTH[32*112], VTL[32*112];    // V transposed (split): [d][row]
  __shared__ float S[112*112];                // logits -> P
  const int tid = threadIdx.x;
  const int wave = tid >> 6, lane = tid & 63;
  const int col16 = lane & 15, quad = lane >> 4;
  const float scale = 0.17677669529663687f;   // 1/sqrt(32)
  const float* base = qkv + (size_t)n * 100 * 768 + h * 32;

  // ---- stage K,V -> LDS (split fp16), zero pad rows 100..111
  for (int idx = tid; idx < 112*32; idx += 256) {
    int r = idx >> 5, d = idx & 31;
    float kv = 0.f, vv = 0.f;
    if (r < 100) {
      const float* p = base + (size_t)r * 768;
      kv = p[256 + d];
      vv = p[512 + d];
    }
    f16 khh, kll, vhh, vll;
    f2h_split(kv, khh, kll);
    f2h_split(vv, vhh, vll);
    KH[idx] = khh; KL[idx] = kll;
    VTH[d*112 + r] = vhh; VTL[d*112 + r] = vll;
  }
  __syncthreads();

  // ---- phase 1: S = scale * Q K^T
  {
    f16x8 bh[7], bl[7];
#pragma unroll
    for (int tn = 0; tn < 7; ++tn) {
      int off = (tn*16 + col16)*32 + quad*8;
      bh[tn] = *(const f16x8*)(KH + off);
      bl[tn] = *(const f16x8*)(KL + off);
    }
#pragma unroll
    for (int ti = 0; ti < 2; ++ti) {
      int tm = wave + ti*4;
      if (tm >= 7) break;                 // wave-uniform
      int m = tm*16 + col16; if (m > 99) m = 99;   // clamp (rows >=100 discarded)
      const float* qp = base + (size_t)m * 768 + quad*8;
      float4 q0 = *(const float4*)(qp);
      float4 q1 = *(const float4*)(qp + 4);
      float qv[8] = {q0.x, q0.y, q0.z, q0.w, q1.x, q1.y, q1.z, q1.w};
      f16x8 ah, al;
#pragma unroll
      for (int j = 0; j < 8; ++j) { f16 hh, ll; f2h_split(qv[j], hh, ll); ah[j] = hh; al[j] = ll; }
      f32x4 acc[7];
#pragma unroll
      for (int tn = 0; tn < 7; ++tn) {
        f32x4 a = {};
        a = __builtin_amdgcn_mfma_f32_16x16x32_f16(al, bh[tn], a, 0, 0, 0);
        a = __builtin_amdgcn_mfma_f32_16x16x32_f16(ah, bl[tn], a, 0, 0, 0);
        a = __builtin_amdgcn_mfma_f32_16x16x32_f16(ah, bh[tn], a, 0, 0, 0);
        acc[tn] = a;
      }
#pragma unroll
      for (int tn = 0; tn < 7; ++tn)
#pragma unroll
        for (int r = 0; r < 4; ++r)
          S[(tm*16 + quad*4 + r)*112 + tn*16 + col16] = acc[tn][r] * scale;
    }
  }
  __syncthreads();

  // ---- phase 2: softmax rows<100 over cols<100; zero cols 100..111
  if (tid < 100) {
    float4* row4 = (float4*)(S + tid*112);
    float m = -1e30f;
    for (int j4 = 0; j4 < 25; ++j4) {
      float4 v = row4[j4];
      m = fmaxf(m, fmaxf(fmaxf(v.x, v.y), fmaxf(v.z, v.w)));
    }
    float s = 0.f;
    for (int j4 = 0; j4 < 25; ++j4) {
      float4 v = row4[j4];
      v.x = __expf(v.x - m); v.y = __expf(v.y - m);
      v.z = __expf(v.z - m); v.w = __expf(v.w - m);
      s += v.x + v.y + v.z + v.w;
      row4[j4] = v;
    }
    float inv = 1.f / s;
    for (int j4 = 0; j4 < 25; ++j4) {
      float4 v = row4[j4];
      v.x *= inv; v.y *= inv; v.z *= inv; v.w *= inv;
      row4[j4] = v;
    }
    float4 z = {0.f, 0.f, 0.f, 0.f};
    row4[25] = z; row4[26] = z; row4[27] = z;
  }
  __syncthreads();

  // ---- phase 3: O = P V  (O 112x32, K padded to 128; frags zeroed for k>=112)
  f16x8 vh[2][4], vl[2][4];
#pragma unroll
  for (int td = 0; td < 2; ++td)
#pragma unroll
    for (int kc = 0; kc < 4; ++kc) {
      if (kc == 3 && quad >= 2) {
        f16x8 z = {};
        vh[td][kc] = z; vl[td][kc] = z;
      } else {
        int off = (td*16 + col16)*112 + kc*32 + quad*8;
        vh[td][kc] = *(const f16x8*)(VTH + off);
        vl[td][kc] = *(const f16x8*)(VTL + off);
      }
    }
#pragma unroll
  for (int ti = 0; ti < 2; ++ti) {
    int tm = wave + ti*4;
    if (tm >= 7) break;                   // wave-uniform
    f32x4 acc[2] = {};
#pragma unroll
    for (int kc = 0; kc < 4; ++kc) {
      f16x8 ph, pl;
      if (kc == 3 && quad >= 2) {
        f16x8 z = {};
        ph = z; pl = z;
      } else {
        const float* pp = S + (tm*16 + col16)*112 + kc*32 + quad*8;
        float4 p0 = *(const float4*)pp;
        float4 p1 = *(const float4*)(pp + 4);
        float pv[8] = {p0.x, p0.y, p0.z, p0.w, p1.x, p1.y, p1.z, p1.w};
#pragma unroll
        for (int j = 0; j < 8; ++j) { f16 hh, ll; f2h_split(pv[j], hh, ll); ph[j] = hh; pl[j] = ll; }
      }
#pragma unroll
      for (int td = 0; td < 2; ++td) {
        acc[td] = __builtin_amdgcn_mfma_f32_16x16x32_f16(pl, vh[td][kc], acc[td], 0, 0, 0);
        acc[td] = __builtin_amdgcn_mfma_f32_16x16x32_f16(ph, vl[td][kc], acc[td], 0, 0, 0);
        acc[td] = __builtin_amdgcn_mfma_f32_16x16x32_f16(ph, vh[td][kc], acc[td], 0, 0, 0);
      }
    }
#pragma unroll
    for (int td = 0; td < 2; ++td) {
#pragma unroll
      for (int r = 0; r < 4; ++r) {
        int m = tm*16 + quad*4 + r;
        if (m < 100) {
          size_t oidx = ((size_t)n*100 + m)*256 + h*32 + td*16 + col16;
          f16 hh, ll; f2h_split(acc[td][r], hh, ll);
          aohi[oidx] = hh;
          aolo[oidx] = ll;
        }
      }
    }
  }
}

// ---------------------------------------------------------------------------
// layernorm: read fp32, write split fp16: one block (256 thr) per row of 256
__global__ __launch_bounds__(256) void ln_kernel(const float* __restrict__ x,
    const float* __restrict__ g, const float* __restrict__ b,
    f16* __restrict__ ohi, f16* __restrict__ olo) {
  size_t m = blockIdx.x;
  int tid = threadIdx.x;
  float v = x[m*256 + tid];
  __shared__ float red[4];
  float s = v;
  for (int o = 32; o > 0; o >>= 1) s += __shfl_down(s, o, 64);
  if ((tid & 63) == 0) red[tid >> 6] = s;
  __syncthreads();
  float mu = (red[0] + red[1] + red[2] + red[3]) * (1.f/256.f);
  float d = v - mu;
  float s2 = d * d;
  for (int o = 32; o > 0; o >>= 1) s2 += __shfl_down(s2, o, 64);
  __syncthreads();
  if ((tid & 63) == 0) red[tid >> 6] = s2;
  __syncthreads();
  float var = (red[0] + red[1] + red[2] + red[3]) * (1.f/256.f);
  float r = d * rsqrtf(var + 1e-5f) * g[tid] + b[tid];
  f16 hh, ll; f2h_split(r, hh, ll);
  ohi[m*256 + tid] = hh;
  olo[m*256 + tid] = ll;
}

// ---------------------------------------------------------------------------
// q_pool + x1 = q_pool @ l1_w^T + l1_b : one block per n (global)
__global__ __launch_bounds__(256) void qpool_x1(const float* __restrict__ q_emb,
    const float* __restrict__ l1_w, const float* __restrict__ l1_b,
    float* __restrict__ x1) {
  int n = blockIdx.x;
  int tid = threadIdx.x;
  __shared__ float pool[256];
  float s = 0.f;
  for (int t = 0; t < 14; ++t) s += q_emb[((size_t)n*14 + t)*256 + tid];
  pool[tid] = s * (1.f/14.f);
  __syncthreads();
  for (int e = tid; e < 600; e += 256) {
    float acc = l1_b[e];
    for (int o = 0; o < 256; ++o) acc += pool[o] * l1_w[(size_t)e*256 + o];
    x1[(size_t)n*600 + e] = acc;
  }
}

// ---------------------------------------------------------------------------
// MLB epilogue
__global__ __launch_bounds__(256) void mlb_kernel(const float* __restrict__ x0,
    const float* __restrict__ x1, const float* __restrict__ lo_w,
    const float* __restrict__ lo_b, float* __restrict__ out) {
  size_t m = blockIdx.x;     // chunk-local row
  size_t n = m / 100;        // chunk-local image
  int tid = threadIdx.x;
  float z[3] = {0.f, 0.f, 0.f};
  float ss = 0.f;
  int cnt = 0;
  for (int e = tid; e < 600; e += 256) {
    float v = x0[m*600 + e] * x1[n*600 + e];
    float r = (v >= 0.f) ? sqrtf(v) : -sqrtf(-v);
    z[cnt++] = r;
    ss += r * r;
  }
  __shared__ float red[4];
  for (int o = 32; o > 0; o >>= 1) ss += __shfl_down(ss, o, 64);
  if ((tid & 63) == 0) red[tid >> 6] = ss;
  __syncthreads();
  ss = red[0] + red[1] + red[2] + red[3];
  float inv = 1.f / fmaxf(sqrtf(ss), 1e-12f);
  float dot = 0.f;
  cnt = 0;
  for (int e = tid; e < 600; e += 256) dot += z[cnt++] * lo_w[e];
  for (int o = 32; o > 0; o >>= 1) dot += __shfl_down(dot, o, 64);
  __syncthreads();
  if ((tid & 63) == 0) red[tid >> 6] = dot;
  __syncthreads();
  if (tid == 0) {
    float sc = (red[0] + red[1] + red[2] + red[3]) * inv + lo_b[0];
    out[m] = 1.f / (1.f + __expf(-sc));
  }
}

// ---------------------------------------------------------------------------
__device__ __forceinline__ float breduce(float v, float* red, int tid) {
  for (int o = 32; o > 0; o >>= 1) v += __shfl_down(v, o, 64);
  if ((tid & 63) == 0) red[tid >> 6] = v;
  __syncthreads();
  float r = red[0] + red[1] + red[2] + red[3];
  __syncthreads();
  return r;
}

// counting module: one block per n (global)
__global__ __launch_bounds__(256) void counter_kernel(
    const float* __restrict__ scores, const float* __restrict__ boxes,
    const float* __restrict__ plw, const float* __restrict__ plc,
    float* __restrict__ pred, float* __restrict__ conf_out) {
  int n = blockIdx.x, tid = threadIdx.x;
  __shared__ float plw_s[8][17], plc_s[8][17];
  __shared__ float sval[128];
  __shared__ int   sidx[128];
  __shared__ float att[36], bx[36][4];
  __shared__ float dist[36][36], scr[36][36], ds2[36][36], sim[36][36];
  __shared__ float rs[36];
  __shared__ float red[4];
  __shared__ float b_f, b_cf;
  __shared__ int   b_i;

  for (int i = tid; i < 136; i += 256) {
    (&plw_s[0][0])[i] = plw[i];
    (&plc_s[0][0])[i] = plc[i];
  }
  if (tid < 128) {
    sval[tid] = (tid < 100) ? scores[(size_t)n*100 + tid] : -1e30f;
    sidx[tid] = tid;
  }
  __syncthreads();

  for (int k = 2; k <= 128; k <<= 1) {
    for (int j = k >> 1; j > 0; j >>= 1) {
      if (tid < 128) {
        int ixj = tid ^ j;
        if (ixj > tid) {
          float va = sval[tid], vb = sval[ixj];
          int   ia = sidx[tid], ib = sidx[ixj];
          bool a_before_b = (va > vb) || (va == vb && ia < ib);
          bool ascending = ((tid & k) == 0);
          bool doswap = ascending ? !a_before_b : a_before_b;
          if (doswap) { sval[tid] = vb; sval[ixj] = va; sidx[tid] = ib; sidx[ixj] = ia; }
        }
      }
      __syncthreads();
    }
  }

  if (tid < 36) {
    att[tid] = sval[tid];
    const float* bp = boxes + ((size_t)n*100 + sidx[tid])*4;
    bx[tid][0] = bp[0]; bx[tid][1] = bp[1]; bx[tid][2] = bp[2]; bx[tid][3] = bp[3];
  }
  __syncthreads();

  for (int idx = tid; idx < 1296; idx += 256) {
    int i = idx / 36, j = idx % 36;
    float x1a = bx[i][0], y1a = bx[i][1], x2a = bx[i][2], y2a = bx[i][3];
    float x1b = bx[j][0], y1b = bx[j][1], x2b = bx[j][2], y2b = bx[j][3];
    float areaA = fmaxf(x2a - x1a, 0.f) * fmaxf(y2a - y1a, 0.f);
    float areaB = fmaxf(x2b - x1b, 0.f) * fmaxf(y2b - y1b, 0.f);
    float iw = fmaxf(fminf(x2a, x2b) - fmaxf(x1a, x1b), 0.f);
    float ih = fmaxf(fminf(y2a, y2b) - fmaxf(y1a, y1b), 0.f);
    float inter = iw * ih;
    float iou = inter / (areaA + areaB - inter + 1e-12f);
    float dd = 1.f - iou;
    float rel = att[i] * att[j];
    dist[i][j] = dd;
    scr[i][j]  = plin_f(plw_s[0], plc_s[0], rel) * plin_f(plw_s[1], plc_s[1], dd);
    ds2[i][j]  = plin_f(plw_s[3], plc_s[3], rel) * plin_f(plw_s[4], plc_s[4], dd);
  }
  __syncthreads();

  for (int idx = tid; idx < 1296; idx += 256) {
    int b = idx / 36, c = idx % 36;
    float p = plin_f(plw_s[2], plc_s[2], 1.f - fabsf(att[b] - att[c]));
    for (int a = 0; a < 36; ++a)
      p *= plin_f(plw_s[2], plc_s[2], 1.f - fabsf(ds2[a][b] - ds2[a][c]));
    sim[b][c] = p;
  }
  __syncthreads();

  if (tid < 36) {
    float s = 0.f;
    for (int c = 0; c < 36; ++c) s += sim[tid][c];
    rs[tid] = s;
  }
  __syncthreads();

  float p1 = 0.f, p4 = 0.f;
  for (int idx = tid; idx < 1296; idx += 256) {
    int b = idx / 36, c = idx % 36;
    p1 += scr[b][c] / (rs[b] * rs[c]);
    p4 += fabsf(plin_f(plw_s[6], plc_s[6], dist[b][c]) - 0.5f);
  }
  float p2 = 0.f, p3 = 0.f;
  if (tid < 36) {
    p2 = plin_f(plw_s[0], plc_s[0], att[tid]*att[tid]) / rs[tid];
    p3 = fabsf(plin_f(plw_s[5], plc_s[5], att[tid]) - 0.5f);
  }
  float s1 = breduce(p1, red, tid);
  float s2 = breduce(p2, red, tid);
  float s3 = breduce(p3, red, tid);
  float s4 = breduce(p4, red, tid);

  if (tid == 0) {
    float total = sqrtf(s1 + s2 + 1e-20f);
    float cf = plin_f(plw_s[7], plc_s[7], s3 * (1.f/36.f) + s4 * (1.f/1296.f));
    float sc = fminf(fmaxf(total, 0.f), 36.f);
    float fl = floorf(sc);
    int ii = (int)fl; if (ii > 36) ii = 36;
    b_f = sc - fl;
    b_i = ii;
    b_cf = cf;
    conf_out[n] = cf;
  }
  __syncthreads();
  if (tid < 37) {
    int ii = b_i;
    int ir = (ii + 1 > 36) ? 36 : ii + 1;
    float v = ((tid == ii) ? (1.f - b_f) : 0.f) + ((tid == ir) ? b_f : 0.f);
    pred[(size_t)n*37 + tid] = v * b_cf;
  }
}

// ---------------------------------------------------------------------------
extern "C" void kernel_launch(void* const* d_in, const int* in_sizes, int n_in,
                              void* d_out, int out_size, void* d_ws, size_t ws_size,
                              hipStream_t stream) {
  const float* v_emb = (const float*)d_in[0];
  const float* q_emb = (const float*)d_in[1];
  const float* boxes = (const float*)d_in[2];
  const float* Wq    = (const float*)d_in[3];
  const float* bq    = (const float*)d_in[4];
  const float* Wk    = (const float*)d_in[5];
  const float* bk    = (const float*)d_in[6];
  const float* Wv    = (const float*)d_in[7];
  const float* bv    = (const float*)d_in[8];
  const float* in_w  = (const float*)d_in[9];
  const float* in_b  = (const float*)d_in[10];
  const float* out_w = (const float*)d_in[11];
  const float* out_b = (const float*)d_in[12];
  const float* ln_g  = (const float*)d_in[13];
  const float* ln_b  = (const float*)d_in[14];
  const float* l0_w  = (const float*)d_in[15];
  const float* l0_b  = (const float*)d_in[16];
  const float* l1_w  = (const float*)d_in[17];
  const float* l1_b  = (const float*)d_in[18];
  const float* lo_w  = (const float*)d_in[19];
  const float* lo_b  = (const float*)d_in[20];
  const float* pw    = (const float*)d_in[21];

  float* ws = (float*)d_ws;
  // persistent fp32 region
  float* plw   = ws + 0;        // 136 (reserve 256)
  float* plc   = ws + 256;      // 136 (reserve 256)
  float* cbuf  = ws + 512;      // 768
  float* x1    = ws + 1280;     // 614400 -> 615680
  // persistent f16 region (element offsets within hb)
  f16* hb = (f16*)(ws + 615680);
  f16* A_hi    = hb + 0;         // 768*256 = 196608
  f16* A_lo    = hb + 196608;
  f16* outw_hi = hb + 393216;    // 256*256 = 65536
  f16* outw_lo = hb + 458752;
  f16* l0w_hi  = hb + 524288;    // 640*256 = 163840
  f16* l0w_lo  = hb + 688128;
  f16* v_hi    = hb + 851968;    // 102400*256 = 26214400
  f16* v_lo    = hb + 27066368;  // end: 53280768 f16 = 26640384 float slots
  const size_t small_floats = 615680 + 26640384;   // 27,256,064 floats (~109 MB)

  // per-image chunk cost (floats): qkv 76800 + inter 25600 + x0 60000
  //   + f16 halves (ao_hi/lo + int_hi/lo = 102400 halves = 51200 floats) = 213600
  size_t avail = (ws_size / 4 > small_floats) ? (ws_size / 4 - small_floats) : 0;
  int NC = 1024;
  while (NC > 32 && (size_t)NC * 213600ull > avail) NC >>= 1;

  float* qkv_c   = ws + small_floats;                 // NC*76800
  float* inter_c = qkv_c   + (size_t)NC * 76800;      // NC*25600
  float* x0_c    = inter_c + (size_t)NC * 25600;      // NC*60000
  f16* ao_hi  = (f16*)(x0_c + (size_t)NC * 60000);    // NC*25600
  f16* ao_lo  = ao_hi + (size_t)NC * 25600;
  f16* int_hi = ao_lo + (size_t)NC * 25600;
  f16* int_lo = int_hi + (size_t)NC * 25600;

  float* out    = (float*)d_out;
  float* scores = out;             // N*R
  float* pred   = out + 102400;    // N*37
  float* conf   = out + 140288;    // N

  prep_plin<<<1, 64, 0, stream>>>(pw, plw, plc);
  fuse_c<<<3, 256, 0, stream>>>(in_w, in_b, bq, bk, bv, cbuf);
  fuse_A<<<768, 256, 0, stream>>>(in_w, Wq, Wk, Wv, A_hi, A_lo);
  split_vec<<<(65536/4 + 255)/256, 256, 0, stream>>>(out_w, outw_hi, outw_lo, 65536/4);
  conv_l0w<<<640, 256, 0, stream>>>(l0_w, l0w_hi, l0w_lo);
  split_vec<<<(26214400/4 + 255)/256, 256, 0, stream>>>(v_emb, v_hi, v_lo, 26214400/4);
  qpool_x1<<<N_, 256, 0, stream>>>(q_emb, l1_w, l1_b, x1);

  for (int n0 = 0; n0 < N_; n0 += NC) {
    const int M = NC * 100;           // divisible by 128 for NC>=32
    const size_t voff = (size_t)n0 * 100 * 256;

    dim3 g1(M / 128, 6);   // O=768
    gemm_f16s<false><<<g1, 256, 0, stream>>>(v_hi + voff, v_lo + voff,
                                             A_hi, A_lo, cbuf, qkv_c, 768);

    attn_mfma<<<NC * H_, 256, 0, stream>>>(qkv_c, ao_hi, ao_lo);

    dim3 g2(M / 128, 2);   // O=256
    gemm_f16s<false><<<g2, 256, 0, stream>>>(ao_hi, ao_lo, outw_hi, outw_lo,
                                             out_b, inter_c, 256);

    ln_kernel<<<M, 256, 0, stream>>>(inter_c, ln_g, ln_b, int_hi, int_lo);

    dim3 g3(M / 128, 5);   // Opad=640, Oreal=600
    gemm_f16s<true><<<g3, 256, 0, stream>>>(int_hi, int_lo, l0w_hi, l0w_lo,
                                            l0_b, x0_c, 600);

    mlb_kernel<<<M, 256, 0, stream>>>(x0_c, x1 + (size_t)n0 * 600, lo_w, lo_b,
                                      scores + (size_t)n0 * 100);
  }

  counter_kernel<<<N_, 256, 0, stream>>>(scores, boxes, plw, plc, pred, conf);
}

// Round 7
// 1228.161 us; speedup vs baseline: 2.5820x; 1.0853x over previous
//
#include <hip/hip_runtime.h>

// Problem constants
#define N_   1024
#define R_   100
#define D_   256
#define T_   14
#define H_   8
#define DH_  32
#define MM_  600
#define OBJ_ 36

typedef _Float16 f16;
typedef __attribute__((ext_vector_type(8))) _Float16 f16x8;
typedef __attribute__((ext_vector_type(4))) _Float16 f16x4v;
typedef __attribute__((ext_vector_type(4))) float f32x4;

// fp32 -> (hi, lo) fp16 split: x ≈ hi + lo with ~22-bit combined mantissa
__device__ __forceinline__ void f2h_split(float x, f16& hi, f16& lo) {
  hi = (_Float16)x;
  lo = (_Float16)(x - (float)hi);
}

// async 16B global->LDS
#define GL16(gp, lp) __builtin_amdgcn_global_load_lds( \
    (const __attribute__((address_space(1))) void*)(gp), \
    (__attribute__((address_space(3))) void*)(lp), 16, 0, 0)

// ---------------------------------------------------------------------------
__device__ __forceinline__ float plin_f(const float* __restrict__ w,
                                        const float* __restrict__ cs, float x) {
  float xc = fminf(fmaxf(x, 0.f), 1.f);
  float y  = 16.f * xc;
  float fy = floorf(y);
  int   i  = (int)fy;              // 0..16
  float f  = y - fy;
  int   ip = i + 1; if (ip > 16) ip = 16;
  return cs[i] + f * w[ip];
}

// ---------------------------------------------------------------------------
__global__ void prep_plin(const float* __restrict__ pw, float* __restrict__ plw,
                          float* __restrict__ plc) {
  int p = threadIdx.x;
  if (p < 8) {
    float w[17];
    float sum = 0.f;
    w[0] = 0.f;
    for (int k = 1; k < 17; ++k) { w[k] = fabsf(pw[p*17 + k]); sum += w[k]; }
    float inv = 1.f / sum;
    float c = 0.f;
    for (int k = 0; k < 17; ++k) {
      float wk = w[k] * inv;
      c += wk;
      plw[p*17 + k] = wk;
      plc[p*17 + k] = c;
    }
  }
}

// ---------------------------------------------------------------------------
__global__ void fuse_c(const float* __restrict__ in_w, const float* __restrict__ in_b,
                       const float* __restrict__ bq, const float* __restrict__ bk,
                       const float* __restrict__ bv, float* __restrict__ c) {
  int i = blockIdx.x * blockDim.x + threadIdx.x;
  if (i < 768) {
    const float* bsel = (i < 256) ? bq : ((i < 512) ? bk : bv);
    float acc = in_b[i];
    for (int o = 0; o < 256; ++o) acc += in_w[(size_t)i*256 + o] * bsel[o];
    c[i] = acc;
  }
}

__global__ __launch_bounds__(256) void fuse_A(const float* __restrict__ in_w,
    const float* __restrict__ Wq, const float* __restrict__ Wk,
    const float* __restrict__ Wv, f16* __restrict__ Ahi, f16* __restrict__ Alo) {
  int i = blockIdx.x;        // 0..767
  int j = threadIdx.x;       // 0..255
  const float* Wsel = (i < 256) ? Wq : ((i < 512) ? Wk : Wv);
  __shared__ float row[256];
  row[j] = in_w[(size_t)i*256 + j];
  __syncthreads();
  float acc = 0.f;
  for (int o = 0; o < 256; ++o) acc += row[o] * Wsel[(size_t)o*256 + j];
  f16 h, l; f2h_split(acc, h, l);
  Ahi[(size_t)i*256 + j] = h;
  Alo[(size_t)i*256 + j] = l;
}

__global__ __launch_bounds__(256) void split_vec(const float* __restrict__ in,
    f16* __restrict__ hi, f16* __restrict__ lo, int n4) {
  int i = blockIdx.x * blockDim.x + threadIdx.x;
  if (i < n4) {
    float4 v = ((const float4*)in)[i];
    union { f16 h[4]; ushort4 u; } H, L;
    f2h_split(v.x, H.h[0], L.h[0]);
    f2h_split(v.y, H.h[1], L.h[1]);
    f2h_split(v.z, H.h[2], L.h[2]);
    f2h_split(v.w, H.h[3], L.h[3]);
    ((ushort4*)hi)[i] = H.u;
    ((ushort4*)lo)[i] = L.u;
  }
}

// 600x256 weight -> split fp16 padded to 640x256 (zero rows beyond 600)
__global__ __launch_bounds__(256) void conv_w600(const float* __restrict__ w,
    f16* __restrict__ hi, f16* __restrict__ lo) {
  int o = blockIdx.x;        // 0..639
  int j = threadIdx.x;       // 0..255
  f16 h = (f16)0.f, l = (f16)0.f;
  if (o < 600) f2h_split(w[(size_t)o*256 + j], h, l);
  hi[(size_t)o*256 + j] = h;
  lo[(size_t)o*256 + j] = l;
}

// q_emb mean-pool -> split fp16 (one block per n)
__global__ __launch_bounds__(256) void pool_split(const float* __restrict__ q_emb,
    f16* __restrict__ qph, f16* __restrict__ qpl) {
  int n = blockIdx.x, tid = threadIdx.x;
  float s = 0.f;
  for (int t = 0; t < 14; ++t) s += q_emb[((size_t)n*14 + t)*256 + tid];
  s *= (1.f/14.f);
  f16 h, l; f2h_split(s, h, l);
  qph[(size_t)n*256 + tid] = h;
  qpl[(size_t)n*256 + tid] = l;
}

// ---------------------------------------------------------------------------
// split-fp16 MFMA GEMM (fp32-accurate): C[m][o] = sum_k X[m][k]*W[o][k] + bias[o]
template<bool BOUND>
__global__ __launch_bounds__(256) void gemm_f16s(
    const f16* __restrict__ Xhi, const f16* __restrict__ Xlo,
    const f16* __restrict__ Whi, const f16* __restrict__ Wlo,
    const float* __restrict__ bias, float* __restrict__ C, int Oreal) {
  __shared__ f16 XsH[128 * 32];
  __shared__ f16 XsL[128 * 32];
  __shared__ f16 WsH[128 * 32];
  __shared__ f16 WsL[128 * 32];
  const int tid  = threadIdx.x;
  const int wave = tid >> 6, lane = tid & 63;
  const int bm = blockIdx.x * 128, bn = blockIdx.y * 128;
  const int wm = (wave & 1) * 64, wn = (wave >> 1) * 64;
  const int col = lane & 15, quad = lane >> 4;

  const int s = wave * 64 + lane;
  const int r0 = s >> 2,         cseg = (s & 3) * 8;
  const int r1 = (s + 256) >> 2;
  const size_t o0 = (size_t)(bm + r0) * 256 + cseg;
  const size_t o1 = (size_t)(bm + r1) * 256 + cseg;
  const size_t p0 = (size_t)(bn + r0) * 256 + cseg;
  const size_t p1 = (size_t)(bn + r1) * 256 + cseg;
  char* XHB = (char*)XsH + wave * 1024;
  char* XLB = (char*)XsL + wave * 1024;
  char* WHB = (char*)WsH + wave * 1024;
  char* WLB = (char*)WsL + wave * 1024;

  f32x4 acc[4][4] = {};

  for (int k0 = 0; k0 < 256; k0 += 32) {
    GL16(Xhi + o0 + k0, XHB);
    GL16(Xhi + o1 + k0, XHB + 4096);
    GL16(Xlo + o0 + k0, XLB);
    GL16(Xlo + o1 + k0, XLB + 4096);
    GL16(Whi + p0 + k0, WHB);
    GL16(Whi + p1 + k0, WHB + 4096);
    GL16(Wlo + p0 + k0, WLB);
    GL16(Wlo + p1 + k0, WLB + 4096);
    __syncthreads();

    f16x8 ah[4], al[4], bh[4], bl[4];
#pragma unroll
    for (int i = 0; i < 4; ++i) {
      int ro = (wm + i*16 + col) * 32 + quad * 8;
      ah[i] = *(const f16x8*)(XsH + ro);
      al[i] = *(const f16x8*)(XsL + ro);
    }
#pragma unroll
    for (int j = 0; j < 4; ++j) {
      int ro = (wn + j*16 + col) * 32 + quad * 8;
      bh[j] = *(const f16x8*)(WsH + ro);
      bl[j] = *(const f16x8*)(WsL + ro);
    }
#pragma unroll
    for (int i = 0; i < 4; ++i)
#pragma unroll
      for (int j = 0; j < 4; ++j) {
        acc[i][j] = __builtin_amdgcn_mfma_f32_16x16x32_f16(al[i], bh[j], acc[i][j], 0, 0, 0);
        acc[i][j] = __builtin_amdgcn_mfma_f32_16x16x32_f16(ah[i], bl[j], acc[i][j], 0, 0, 0);
        acc[i][j] = __builtin_amdgcn_mfma_f32_16x16x32_f16(ah[i], bh[j], acc[i][j], 0, 0, 0);
      }
    __syncthreads();
  }

#pragma unroll
  for (int j = 0; j < 4; ++j) {
    int o = bn + wn + j*16 + col;
    if (BOUND && o >= Oreal) continue;
    float bo = bias[o];
#pragma unroll
    for (int i = 0; i < 4; ++i) {
#pragma unroll
      for (int r = 0; r < 4; ++r) {
        int m = bm + wm + i*16 + quad*4 + r;
        C[(size_t)m * Oreal + o] = acc[i][j][r] + bo;
      }
    }
  }
}

// ---------------------------------------------------------------------------
// out-proj GEMM + fused LayerNorm: tile 128 rows x FULL 256 cols per block.
// inter = LN(ao @ out_w^T + out_b); writes split f16 directly.
__global__ __launch_bounds__(256) void gemm2_ln(
    const f16* __restrict__ Xhi, const f16* __restrict__ Xlo,
    const f16* __restrict__ Whi, const f16* __restrict__ Wlo,
    const float* __restrict__ bias, const float* __restrict__ g,
    const float* __restrict__ b, f16* __restrict__ ohi, f16* __restrict__ olo) {
  __shared__ f16 XsH[128 * 32];
  __shared__ f16 XsL[128 * 32];
  __shared__ f16 WsH[256 * 32];
  __shared__ f16 WsL[256 * 32];
  __shared__ float gbb[768];   // g | b | bias
  const int tid  = threadIdx.x;
  const int wave = tid >> 6, lane = tid & 63;
  const int bm = blockIdx.x * 128;
  const int wm = wave * 32;
  const int col16 = lane & 15, quad = lane >> 4;

  for (int i = tid; i < 768; i += 256)
    gbb[i] = (i < 256) ? g[i] : ((i < 512) ? b[i - 256] : bias[i - 512]);

  const int s = wave * 64 + lane;
  const int rx0 = s >> 2, cseg = (s & 3) * 8;
  const int rx1 = (s + 256) >> 2;
  const size_t o0 = (size_t)(bm + rx0) * 256 + cseg;
  const size_t o1 = (size_t)(bm + rx1) * 256 + cseg;
  char* XHB = (char*)XsH + wave * 1024;
  char* XLB = (char*)XsL + wave * 1024;

  f32x4 acc[2][16] = {};

  for (int k0 = 0; k0 < 256; k0 += 32) {
    GL16(Xhi + o0 + k0, XHB);
    GL16(Xhi + o1 + k0, XHB + 4096);
    GL16(Xlo + o0 + k0, XLB);
    GL16(Xlo + o1 + k0, XLB + 4096);
#pragma unroll
    for (int is = 0; is < 4; ++is) {
      int sw = is * 256 + s;
      size_t wo = (size_t)(sw >> 2) * 256 + (sw & 3) * 8 + k0;
      GL16(Whi + wo, (char*)WsH + is * 4096 + wave * 1024);
      GL16(Wlo + wo, (char*)WsL + is * 4096 + wave * 1024);
    }
    __syncthreads();

    f16x8 ah[2], al[2];
#pragma unroll
    for (int i = 0; i < 2; ++i) {
      int ro = (wm + i*16 + col16) * 32 + quad * 8;
      ah[i] = *(const f16x8*)(XsH + ro);
      al[i] = *(const f16x8*)(XsL + ro);
    }
#pragma unroll
    for (int j = 0; j < 16; ++j) {
      int ro = (j*16 + col16) * 32 + quad * 8;
      f16x8 bh = *(const f16x8*)(WsH + ro);
      f16x8 bl = *(const f16x8*)(WsL + ro);
#pragma unroll
      for (int i = 0; i < 2; ++i) {
        acc[i][j] = __builtin_amdgcn_mfma_f32_16x16x32_f16(al[i], bh, acc[i][j], 0, 0, 0);
        acc[i][j] = __builtin_amdgcn_mfma_f32_16x16x32_f16(ah[i], bl, acc[i][j], 0, 0, 0);
        acc[i][j] = __builtin_amdgcn_mfma_f32_16x16x32_f16(ah[i], bh, acc[i][j], 0, 0, 0);
      }
    }
    __syncthreads();
  }

  // epilogue: bias + LayerNorm per row, write split f16
  // row m = bm + wm + i*16 + quad*4 + r; col = j*16 + col16
#pragma unroll
  for (int i = 0; i < 2; ++i) {
#pragma unroll
    for (int r = 0; r < 4; ++r) {
      float x[16];
      float sum = 0.f;
#pragma unroll
      for (int j = 0; j < 16; ++j) {
        float v = acc[i][j][r] + gbb[512 + j*16 + col16];
        x[j] = v;
        sum += v;
      }
#pragma unroll
      for (int msk = 1; msk < 16; msk <<= 1) sum += __shfl_xor(sum, msk, 64);
      float mu = sum * (1.f/256.f);
      float s2 = 0.f;
#pragma unroll
      for (int j = 0; j < 16; ++j) { float d = x[j] - mu; s2 += d * d; }
#pragma unroll
      for (int msk = 1; msk < 16; msk <<= 1) s2 += __shfl_xor(s2, msk, 64);
      float inv = rsqrtf(s2 * (1.f/256.f) + 1e-5f);
      size_t m = (size_t)(bm + wm + i*16 + quad*4 + r);
#pragma unroll
      for (int j = 0; j < 16; ++j) {
        int col = j*16 + col16;
        float yv = (x[j] - mu) * inv * gbb[col] + gbb[256 + col];
        f16 hh, ll; f2h_split(yv, hh, ll);
        ohi[m*256 + col] = hh;
        olo[m*256 + col] = ll;
      }
    }
  }
}

// ---------------------------------------------------------------------------
// MFMA attention: one block per (local n, h). qkv (nc,100,768) fp32: q|k|v.
// VT stride padded 112->116 (2-way bank-free writes); reads via 8B f16x4 pairs.
__global__ __launch_bounds__(256) void attn_mfma(const float* __restrict__ qkv,
    f16* __restrict__ aohi, f16* __restrict__ aolo) {
  const int n = blockIdx.x >> 3;
  const int h = blockIdx.x & 7;
  __shared__ f16 KH[112*32], KL[112*32];      // K rows (split)
  __shared__ f16 VTH[32*116], VTL[32*116];    // V transposed (split), stride 116
  __shared__ float S[112*112];                // logits -> P
  const int tid = threadIdx.x;
  const int wave = tid >> 6, lane = tid & 63;
  const int col16 = lane & 15, quad = lane >> 4;
  const float scale = 0.17677669529663687f;   // 1/sqrt(32)
  const float* base = qkv + (size_t)n * 100 * 768 + h * 32;

  for (int idx = tid; idx < 112*32; idx += 256) {
    int r = idx >> 5, d = idx & 31;
    float kv = 0.f, vv = 0.f;
    if (r < 100) {
      const float* p = base + (size_t)r * 768;
      kv = p[256 + d];
      vv = p[512 + d];
    }
    f16 khh, kll, vhh, vll;
    f2h_split(kv, khh, kll);
    f2h_split(vv, vhh, vll);
    KH[idx] = khh; KL[idx] = kll;
    VTH[d*116 + r] = vhh; VTL[d*116 + r] = vll;
  }
  __syncthreads();

  // ---- phase 1: S = scale * Q K^T
  {
    f16x8 bh[7], bl[7];
#pragma unroll
    for (int tn = 0; tn < 7; ++tn) {
      int off = (tn*16 + col16)*32 + quad*8;
      bh[tn] = *(const f16x8*)(KH + off);
      bl[tn] = *(const f16x8*)(KL + off);
    }
#pragma unroll
    for (int ti = 0; ti < 2; ++ti) {
      int tm = wave + ti*4;
      if (tm >= 7) break;                 // wave-uniform
      int m = tm*16 + col16; if (m > 99) m = 99;
      const float* qp = base + (size_t)m * 768 + quad*8;
      float4 q0 = *(const float4*)(qp);
      float4 q1 = *(const float4*)(qp + 4);
      float qv[8] = {q0.x, q0.y, q0.z, q0.w, q1.x, q1.y, q1.z, q1.w};
      f16x8 ah, al;
#pragma unroll
      for (int j = 0; j < 8; ++j) { f16 hh, ll; f2h_split(qv[j], hh, ll); ah[j] = hh; al[j] = ll; }
      f32x4 acc[7];
#pragma unroll
      for (int tn = 0; tn < 7; ++tn) {
        f32x4 a = {};
        a = __builtin_amdgcn_mfma_f32_16x16x32_f16(al, bh[tn], a, 0, 0, 0);
        a = __builtin_amdgcn_mfma_f32_16x16x32_f16(ah, bl[tn], a, 0, 0, 0);
        a = __builtin_amdgcn_mfma_f32_16x16x32_f16(ah, bh[tn], a, 0, 0, 0);
        acc[tn] = a;
      }
#pragma unroll
      for (int tn = 0; tn < 7; ++tn)
#pragma unroll
        for (int r = 0; r < 4; ++r)
          S[(tm*16 + quad*4 + r)*112 + tn*16 + col16] = acc[tn][r] * scale;
    }
  }
  __syncthreads();

  // ---- phase 2: softmax rows<100 over cols<100; zero cols 100..111
  if (tid < 100) {
    float4* row4 = (float4*)(S + tid*112);
    float m = -1e30f;
    for (int j4 = 0; j4 < 25; ++j4) {
      float4 v = row4[j4];
      m = fmaxf(m, fmaxf(fmaxf(v.x, v.y), fmaxf(v.z, v.w)));
    }
    float s = 0.f;
    for (int j4 = 0; j4 < 25; ++j4) {
      float4 v = row4[j4];
      v.x = __expf(v.x - m); v.y = __expf(v.y - m);
      v.z = __expf(v.z - m); v.w = __expf(v.w - m);
      s += v.x + v.y + v.z + v.w;
      row4[j4] = v;
    }
    float inv = 1.f / s;
    for (int j4 = 0; j4 < 25; ++j4) {
      float4 v = row4[j4];
      v.x *= inv; v.y *= inv; v.z *= inv; v.w *= inv;
      row4[j4] = v;
    }
    float4 z = {0.f, 0.f, 0.f, 0.f};
    row4[25] = z; row4[26] = z; row4[27] = z;
  }
  __syncthreads();

  // ---- phase 3: O = P V  (K padded to 128; frags zeroed for k>=112)
  f16x8 vh[2][4], vl[2][4];
#pragma unroll
  for (int td = 0; td < 2; ++td)
#pragma unroll
    for (int kc = 0; kc < 4; ++kc) {
      if (kc == 3 && quad >= 2) {
        f16x8 z = {};
        vh[td][kc] = z; vl[td][kc] = z;
      } else {
        int off = (td*16 + col16)*116 + kc*32 + quad*8;
        f16x4v h0 = *(const f16x4v*)(VTH + off);
        f16x4v h1 = *(const f16x4v*)(VTH + off + 4);
        f16x4v l0 = *(const f16x4v*)(VTL + off);
        f16x4v l1 = *(const f16x4v*)(VTL + off + 4);
        f16x8 hv, lv;
#pragma unroll
        for (int t = 0; t < 4; ++t) { hv[t] = h0[t]; hv[t+4] = h1[t]; lv[t] = l0[t]; lv[t+4] = l1[t]; }
        vh[td][kc] = hv; vl[td][kc] = lv;
      }
    }
#pragma unroll
  for (int ti = 0; ti < 2; ++ti) {
    int tm = wave + ti*4;
    if (tm >= 7) break;                   // wave-uniform
    f32x4 acc[2] = {};
#pragma unroll
    for (int kc = 0; kc < 4; ++kc) {
      f16x8 ph, pl;
      if (kc == 3 && quad >= 2) {
        f16x8 z = {};
        ph = z; pl = z;
      } else {
        const float* pp = S + (tm*16 + col16)*112 + kc*32 + quad*8;
        float4 p0 = *(const float4*)pp;
        float4 p1 = *(const float4*)(pp + 4);
        float pv[8] = {p0.x, p0.y, p0.z, p0.w, p1.x, p1.y, p1.z, p1.w};
#pragma unroll
        for (int j = 0; j < 8; ++j) { f16 hh, ll; f2h_split(pv[j], hh, ll); ph[j] = hh; pl[j] = ll; }
      }
#pragma unroll
      for (int td = 0; td < 2; ++td) {
        acc[td] = __builtin_amdgcn_mfma_f32_16x16x32_f16(pl, vh[td][kc], acc[td], 0, 0, 0);
        acc[td] = __builtin_amdgcn_mfma_f32_16x16x32_f16(ph, vl[td][kc], acc[td], 0, 0, 0);
        acc[td] = __builtin_amdgcn_mfma_f32_16x16x32_f16(ph, vh[td][kc], acc[td], 0, 0, 0);
      }
    }
#pragma unroll
    for (int td = 0; td < 2; ++td) {
#pragma unroll
      for (int r = 0; r < 4; ++r) {
        int m = tm*16 + quad*4 + r;
        if (m < 100) {
          size_t oidx = ((size_t)n*100 + m)*256 + h*32 + td*16 + col16;
          f16 hh, ll; f2h_split(acc[td][r], hh, ll);
          aohi[oidx] = hh;
          aolo[oidx] = ll;
        }
      }
    }
  }
}

// ---------------------------------------------------------------------------
// MLB epilogue
__global__ __launch_bounds__(256) void mlb_kernel(const float* __restrict__ x0,
    const float* __restrict__ x1, const float* __restrict__ lo_w,
    const float* __restrict__ lo_b, float* __restrict__ out) {
  size_t m = blockIdx.x;
  size_t n = m / 100;
  int tid = threadIdx.x;
  float z[3] = {0.f, 0.f, 0.f};
  float ss = 0.f;
  int cnt = 0;
  for (int e = tid; e < 600; e += 256) {
    float v = x0[m*600 + e] * x1[n*600 + e];
    float r = (v >= 0.f) ? sqrtf(v) : -sqrtf(-v);
    z[cnt++] = r;
    ss += r * r;
  }
  __shared__ float red[4];
  for (int o = 32; o > 0; o >>= 1) ss += __shfl_down(ss, o, 64);
  if ((tid & 63) == 0) red[tid >> 6] = ss;
  __syncthreads();
  ss = red[0] + red[1] + red[2] + red[3];
  float inv = 1.f / fmaxf(sqrtf(ss), 1e-12f);
  float dot = 0.f;
  cnt = 0;
  for (int e = tid; e < 600; e += 256) dot += z[cnt++] * lo_w[e];
  for (int o = 32; o > 0; o >>= 1) dot += __shfl_down(dot, o, 64);
  __syncthreads();
  if ((tid & 63) == 0) red[tid >> 6] = dot;
  __syncthreads();
  if (tid == 0) {
    float sc = (red[0] + red[1] + red[2] + red[3]) * inv + lo_b[0];
    out[m] = 1.f / (1.f + __expf(-sc));
  }
}

// ---------------------------------------------------------------------------
__device__ __forceinline__ float breduce(float v, float* red, int tid) {
  for (int o = 32; o > 0; o >>= 1) v += __shfl_down(v, o, 64);
  if ((tid & 63) == 0) red[tid >> 6] = v;
  __syncthreads();
  float r = red[0] + red[1] + red[2] + red[3];
  __syncthreads();
  return r;
}

// counting module: one block per n (global)
__global__ __launch_bounds__(256) void counter_kernel(
    const float* __restrict__ scores, const float* __restrict__ boxes,
    const float* __restrict__ plw, const float* __restrict__ plc,
    float* __restrict__ pred, float* __restrict__ conf_out) {
  int n = blockIdx.x, tid = threadIdx.x;
  __shared__ float plw_s[8][17], plc_s[8][17];
  __shared__ float sval[128];
  __shared__ int   sidx[128];
  __shared__ float att[36], bx[36][4];
  __shared__ float dist[36][36], scr[36][36], ds2[36][36], sim[36][36];
  __shared__ float rs[36];
  __shared__ float red[4];
  __shared__ float b_f, b_cf;
  __shared__ int   b_i;

  for (int i = tid; i < 136; i += 256) {
    (&plw_s[0][0])[i] = plw[i];
    (&plc_s[0][0])[i] = plc[i];
  }
  if (tid < 128) {
    sval[tid] = (tid < 100) ? scores[(size_t)n*100 + tid] : -1e30f;
    sidx[tid] = tid;
  }
  __syncthreads();

  for (int k = 2; k <= 128; k <<= 1) {
    for (int j = k >> 1; j > 0; j >>= 1) {
      if (tid < 128) {
        int ixj = tid ^ j;
        if (ixj > tid) {
          float va = sval[tid], vb = sval[ixj];
          int   ia = sidx[tid], ib = sidx[ixj];
          bool a_before_b = (va > vb) || (va == vb && ia < ib);
          bool ascending = ((tid & k) == 0);
          bool doswap = ascending ? !a_before_b : a_before_b;
          if (doswap) { sval[tid] = vb; sval[ixj] = va; sidx[tid] = ib; sidx[ixj] = ia; }
        }
      }
      __syncthreads();
    }
  }

  if (tid < 36) {
    att[tid] = sval[tid];
    const float* bp = boxes + ((size_t)n*100 + sidx[tid])*4;
    bx[tid][0] = bp[0]; bx[tid][1] = bp[1]; bx[tid][2] = bp[2]; bx[tid][3] = bp[3];
  }
  __syncthreads();

  for (int idx = tid; idx < 1296; idx += 256) {
    int i = idx / 36, j = idx % 36;
    float x1a = bx[i][0], y1a = bx[i][1], x2a = bx[i][2], y2a = bx[i][3];
    float x1b = bx[j][0], y1b = bx[j][1], x2b = bx[j][2], y2b = bx[j][3];
    float areaA = fmaxf(x2a - x1a, 0.f) * fmaxf(y2a - y1a, 0.f);
    float areaB = fmaxf(x2b - x1b, 0.f) * fmaxf(y2b - y1b, 0.f);
    float iw = fmaxf(fminf(x2a, x2b) - fmaxf(x1a, x1b), 0.f);
    float ih = fmaxf(fminf(y2a, y2b) - fmaxf(y1a, y1b), 0.f);
    float inter = iw * ih;
    float iou = inter / (areaA + areaB - inter + 1e-12f);
    float dd = 1.f - iou;
    float rel = att[i] * att[j];
    dist[i][j] = dd;
    scr[i][j]  = plin_f(plw_s[0], plc_s[0], rel) * plin_f(plw_s[1], plc_s[1], dd);
    ds2[i][j]  = plin_f(plw_s[3], plc_s[3], rel) * plin_f(plw_s[4], plc_s[4], dd);
  }
  __syncthreads();

  for (int idx = tid; idx < 1296; idx += 256) {
    int b = idx / 36, c = idx % 36;
    float p = plin_f(plw_s[2], plc_s[2], 1.f - fabsf(att[b] - att[c]));
    for (int a = 0; a < 36; ++a)
      p *= plin_f(plw_s[2], plc_s[2], 1.f - fabsf(ds2[a][b] - ds2[a][c]));
    sim[b][c] = p;
  }
  __syncthreads();

  if (tid < 36) {
    float s = 0.f;
    for (int c = 0; c < 36; ++c) s += sim[tid][c];
    rs[tid] = s;
  }
  __syncthreads();

  float p1 = 0.f, p4 = 0.f;
  for (int idx = tid; idx < 1296; idx += 256) {
    int b = idx / 36, c = idx % 36;
    p1 += scr[b][c] / (rs[b] * rs[c]);
    p4 += fabsf(plin_f(plw_s[6], plc_s[6], dist[b][c]) - 0.5f);
  }
  float p2 = 0.f, p3 = 0.f;
  if (tid < 36) {
    p2 = plin_f(plw_s[0], plc_s[0], att[tid]*att[tid]) / rs[tid];
    p3 = fabsf(plin_f(plw_s[5], plc_s[5], att[tid]) - 0.5f);
  }
  float s1 = breduce(p1, red, tid);
  float s2 = breduce(p2, red, tid);
  float s3 = breduce(p3, red, tid);
  float s4 = breduce(p4, red, tid);

  if (tid == 0) {
    float total = sqrtf(s1 + s2 + 1e-20f);
    float cf = plin_f(plw_s[7], plc_s[7], s3 * (1.f/36.f) + s4 * (1.f/1296.f));
    float sc = fminf(fmaxf(total, 0.f), 36.f);
    float fl = floorf(sc);
    int ii = (int)fl; if (ii > 36) ii = 36;
    b_f = sc - fl;
    b_i = ii;
    b_cf = cf;
    conf_out[n] = cf;
  }
  __syncthreads();
  if (tid < 37) {
    int ii = b_i;
    int ir = (ii + 1 > 36) ? 36 : ii + 1;
    float v = ((tid == ii) ? (1.f - b_f) : 0.f) + ((tid == ir) ? b_f : 0.f);
    pred[(size_t)n*37 + tid] = v * b_cf;
  }
}

// ---------------------------------------------------------------------------
extern "C" void kernel_launch(void* const* d_in, const int* in_sizes, int n_in,
                              void* d_out, int out_size, void* d_ws, size_t ws_size,
                              hipStream_t stream) {
  const float* v_emb = (const float*)d_in[0];
  const float* q_emb = (const float*)d_in[1];
  const float* boxes = (const float*)d_in[2];
  const float* Wq    = (const float*)d_in[3];
  const float* bq    = (const float*)d_in[4];
  const float* Wk    = (const float*)d_in[5];
  const float* bk    = (const float*)d_in[6];
  const float* Wv    = (const float*)d_in[7];
  const float* bv    = (const float*)d_in[8];
  const float* in_w  = (const float*)d_in[9];
  const float* in_b  = (const float*)d_in[10];
  const float* out_w = (const float*)d_in[11];
  const float* out_b = (const float*)d_in[12];
  const float* ln_g  = (const float*)d_in[13];
  const float* ln_b  = (const float*)d_in[14];
  const float* l0_w  = (const float*)d_in[15];
  const float* l0_b  = (const float*)d_in[16];
  const float* l1_w  = (const float*)d_in[17];
  const float* l1_b  = (const float*)d_in[18];
  const float* lo_w  = (const float*)d_in[19];
  const float* lo_b  = (const float*)d_in[20];
  const float* pw    = (const float*)d_in[21];

  float* ws = (float*)d_ws;
  // persistent fp32 region
  float* plw   = ws + 0;        // 136 (reserve 256)
  float* plc   = ws + 256;      // 136 (reserve 256)
  float* cbuf  = ws + 512;      // 768
  float* x1    = ws + 1280;     // 614400 -> 615680
  // persistent f16 region (element offsets within hb)
  f16* hb = (f16*)(ws + 615680);
  f16* A_hi    = hb + 0;         // 768*256 = 196608
  f16* A_lo    = hb + 196608;
  f16* outw_hi = hb + 393216;    // 256*256 = 65536
  f16* outw_lo = hb + 458752;
  f16* l0w_hi  = hb + 524288;    // 640*256 = 163840
  f16* l0w_lo  = hb + 688128;
  f16* l1w_hi  = hb + 851968;    // 640*256 = 163840
  f16* l1w_lo  = hb + 1015808;
  f16* qp_hi   = hb + 1179648;   // 1024*256 = 262144
  f16* qp_lo   = hb + 1441792;
  f16* v_hi    = hb + 1703936;   // 102400*256 = 26214400
  f16* v_lo    = hb + 27918336;  // end 54132736 f16 = 27066368 float slots
  const size_t small_floats = 615680 + 27066368;   // 27,682,048 floats (~111 MB)

  // per-image chunk cost (floats): qkv 76800 + x0 60000 + 4*12800 (f16 halves) = 188000
  size_t avail = (ws_size / 4 > small_floats) ? (ws_size / 4 - small_floats) : 0;
  int NC = 1024;
  while (NC > 32 && (size_t)NC * 188000ull > avail) NC >>= 1;

  float* qkv_c = ws + small_floats;                 // NC*76800
  float* x0_c  = qkv_c + (size_t)NC * 76800;        // NC*60000
  f16* ao_hi  = (f16*)(x0_c + (size_t)NC * 60000);  // NC*25600
  f16* ao_lo  = ao_hi + (size_t)NC * 25600;
  f16* int_hi = ao_lo + (size_t)NC * 25600;
  f16* int_lo = int_hi + (size_t)NC * 25600;

  float* out    = (float*)d_out;
  float* scores = out;             // N*R
  float* pred   = out + 102400;    // N*37
  float* conf   = out + 140288;    // N

  prep_plin<<<1, 64, 0, stream>>>(pw, plw, plc);
  fuse_c<<<3, 256, 0, stream>>>(in_w, in_b, bq, bk, bv, cbuf);
  fuse_A<<<768, 256, 0, stream>>>(in_w, Wq, Wk, Wv, A_hi, A_lo);
  split_vec<<<(65536/4 + 255)/256, 256, 0, stream>>>(out_w, outw_hi, outw_lo, 65536/4);
  conv_w600<<<640, 256, 0, stream>>>(l0_w, l0w_hi, l0w_lo);
  conv_w600<<<640, 256, 0, stream>>>(l1_w, l1w_hi, l1w_lo);
  split_vec<<<(26214400/4 + 255)/256, 256, 0, stream>>>(v_emb, v_hi, v_lo, 26214400/4);
  pool_split<<<N_, 256, 0, stream>>>(q_emb, qp_hi, qp_lo);
  {
    dim3 gx(1024/128, 5);   // x1 = q_pool @ l1_w^T + l1_b  (M=1024, Opad=640)
    gemm_f16s<true><<<gx, 256, 0, stream>>>(qp_hi, qp_lo, l1w_hi, l1w_lo,
                                            l1_b, x1, 600);
  }

  for (int n0 = 0; n0 < N_; n0 += NC) {
    const int M = NC * 100;
    const size_t voff = (size_t)n0 * 100 * 256;

    dim3 g1(M / 128, 6);   // O=768
    gemm_f16s<false><<<g1, 256, 0, stream>>>(v_hi + voff, v_lo + voff,
                                             A_hi, A_lo, cbuf, qkv_c, 768);

    attn_mfma<<<NC * H_, 256, 0, stream>>>(qkv_c, ao_hi, ao_lo);

    // out-proj + fused LayerNorm -> split f16
    gemm2_ln<<<M / 128, 256, 0, stream>>>(ao_hi, ao_lo, outw_hi, outw_lo,
                                          out_b, ln_g, ln_b, int_hi, int_lo);

    dim3 g3(M / 128, 5);   // Opad=640, Oreal=600
    gemm_f16s<true><<<g3, 256, 0, stream>>>(int_hi, int_lo, l0w_hi, l0w_lo,
                                            l0_b, x0_c, 600);

    mlb_kernel<<<M, 256, 0, stream>>>(x0_c, x1 + (size_t)n0 * 600, lo_w, lo_b,
                                      scores + (size_t)n0 * 100);
  }

  counter_kernel<<<N_, 256, 0, stream>>>(scores, boxes, plw, plc, pred, conf);
}